// Round 1
// baseline (1343.007 us; speedup 1.0000x reference)
//
#include <hip/hip_runtime.h>
#include <cstdint>
#include <cstddef>

// ---------------------------------------------------------------------------
// Transformer block, B=2 T=2048 C=2048 NH=16 NKV=4 HD=128 DFF=8192, gfx950.
// R0: correct baseline using m97-style MFMA GEMM + MFMA flash attention.
// ---------------------------------------------------------------------------

#define B_    2
#define T_    2048
#define C_    2048
#define NH_   16
#define NKV_  4
#define HD_   128
#define DFF_  8192
#define EPS_  1.1920928955078125e-07f   // jnp.finfo(float32).eps

typedef short          bf16x8 __attribute__((ext_vector_type(8)));
typedef float          f32x4  __attribute__((ext_vector_type(4)));
typedef unsigned short u16;
typedef unsigned short u16x8  __attribute__((ext_vector_type(8)));
typedef unsigned short u16x4  __attribute__((ext_vector_type(4)));

__device__ __forceinline__ u16 f2bf(float f) {
    unsigned u = __float_as_uint(f);
    unsigned r = u + 0x7fffu + ((u >> 16) & 1u);   // RNE; inputs are finite
    return (u16)(r >> 16);
}

__device__ __forceinline__ void load_lds16(const void* g, void* l) {
    // 16B per lane, LDS dest = wave-uniform base + lane*16 (guide §5 caveat)
    __builtin_amdgcn_global_load_lds(
        (__attribute__((address_space(1))) void*)(g),
        (__attribute__((address_space(3))) void*)(l), 16, 0, 0);
}

// ---------------------------------------------------------------------------
// Weight transpose + cast: src [K][N] f32  ->  dst [N][K] bf16
// ---------------------------------------------------------------------------
__global__ void transpose_cast(const float* __restrict__ src, u16* __restrict__ dst,
                               int K, int N) {
    __shared__ float tile[32][33];
    int tx = threadIdx.x & 31;
    int ty = threadIdx.x >> 5;            // 0..7
    int n0 = blockIdx.x * 32;
    int k0 = blockIdx.y * 32;
    for (int j = 0; j < 4; ++j)
        tile[ty + j * 8][tx] = src[(size_t)(k0 + ty + j * 8) * N + n0 + tx];
    __syncthreads();
    for (int j = 0; j < 4; ++j)
        dst[(size_t)(n0 + ty + j * 8) * K + k0 + tx] = f2bf(tile[tx][ty + j * 8]);
}

// ---------------------------------------------------------------------------
// RMSNorm over rows of [M][2048] f32 -> bf16
// ---------------------------------------------------------------------------
__global__ void rmsnorm_rows(const float* __restrict__ x, u16* __restrict__ out) {
    int row = blockIdx.x;
    const float4* xr = (const float4*)(x + (size_t)row * C_);
    float4 a = xr[threadIdx.x];
    float4 b = xr[threadIdx.x + 256];
    float ss = a.x * a.x + a.y * a.y + a.z * a.z + a.w * a.w
             + b.x * b.x + b.y * b.y + b.z * b.z + b.w * b.w;
    for (int m = 1; m < 64; m <<= 1) ss += __shfl_xor(ss, m, 64);
    __shared__ float part[4];
    if ((threadIdx.x & 63) == 0) part[threadIdx.x >> 6] = ss;
    __syncthreads();
    float tot = part[0] + part[1] + part[2] + part[3];
    float sc = rsqrtf(tot * (1.0f / C_) + EPS_);
    u16x4 o1, o2;
    o1[0] = f2bf(a.x * sc); o1[1] = f2bf(a.y * sc); o1[2] = f2bf(a.z * sc); o1[3] = f2bf(a.w * sc);
    o2[0] = f2bf(b.x * sc); o2[1] = f2bf(b.y * sc); o2[2] = f2bf(b.z * sc); o2[3] = f2bf(b.w * sc);
    u16x4* orow = (u16x4*)(out + (size_t)row * C_);
    orow[threadIdx.x]       = o1;
    orow[threadIdx.x + 256] = o2;
}

// ---------------------------------------------------------------------------
// RoPE + per-head RMSNorm: X f32 [B,T,nh,128] -> Out bf16. One wave per row.
// ---------------------------------------------------------------------------
__global__ void rope_rms(const float* __restrict__ X, const float* __restrict__ cosb,
                         const float* __restrict__ sinb, u16* __restrict__ Out,
                         int nheads) {
    int wid  = (int)((blockIdx.x * blockDim.x + threadIdx.x) >> 6);
    int lane = threadIdx.x & 63;
    int t = (wid / nheads) % T_;
    size_t base = (size_t)wid * HD_;
    float x1 = X[base + lane];
    float x2 = X[base + 64 + lane];
    float c  = cosb[t * 64 + lane];
    float sn = sinb[t * 64 + lane];
    float r1 = x1 * c + x2 * sn;
    float r2 = x2 * c - x1 * sn;
    float ss = r1 * r1 + r2 * r2;
    for (int m = 1; m < 64; m <<= 1) ss += __shfl_xor(ss, m, 64);
    float sc = rsqrtf(ss * (1.0f / HD_) + EPS_);
    Out[base + lane]      = f2bf(r1 * sc);
    Out[base + 64 + lane] = f2bf(r2 * sc);
}

// ---------------------------------------------------------------------------
// GEMM: C[M][N] = A[M][K](bf16) * Bt[N][K](bf16)^T, 128x128x32 tile, m97-style.
// EPI: 0=store f32, 1=store bf16, 2=relu^2 -> bf16, 3=residual(f32)+ -> f32
// ---------------------------------------------------------------------------
template <int EPI>
__launch_bounds__(256, 2)
__global__ void gemm_bt(const u16* __restrict__ A, const u16* __restrict__ Bt,
                        void* __restrict__ out, const float* __restrict__ res,
                        int M, int N, int K) {
    __shared__ __attribute__((aligned(16))) u16 As[128 * 32];
    __shared__ __attribute__((aligned(16))) u16 Bs[128 * 32];
    int tid  = threadIdx.x;
    int lane = tid & 63;
    int wave = tid >> 6;
    int quad = lane >> 4;
    int l16  = lane & 15;
    int bn = blockIdx.x, bm = blockIdx.y;
    int wm = wave >> 1, wn = wave & 1;

    int srow = lane >> 2;          // 0..15
    int scol = (lane & 3) * 8;     // 0,8,16,24
    const u16* Ag = A  + (size_t)(bm * 128 + wave * 32 + srow) * K + scol;
    const u16* Bg = Bt + (size_t)(bn * 128 + wave * 32 + srow) * K + scol;
    u16* Asw = &As[(wave * 32) * 32];
    u16* Bsw = &Bs[(wave * 32) * 32];

    f32x4 zero = {0.f, 0.f, 0.f, 0.f};
    f32x4 acc[4][4];
    for (int i = 0; i < 4; ++i)
        for (int j = 0; j < 4; ++j) acc[i][j] = zero;

    for (int k0 = 0; k0 < K; k0 += 32) {
        load_lds16(Ag + k0,                  Asw);
        load_lds16(Ag + k0 + (size_t)16 * K, Asw + 16 * 32);
        load_lds16(Bg + k0,                  Bsw);
        load_lds16(Bg + k0 + (size_t)16 * K, Bsw + 16 * 32);
        __syncthreads();
        bf16x8 af[4], bfr[4];
        for (int t = 0; t < 4; ++t) {
            af[t]  = *(const bf16x8*)&As[(wm * 64 + t * 16 + l16) * 32 + quad * 8];
            bfr[t] = *(const bf16x8*)&Bs[(wn * 64 + t * 16 + l16) * 32 + quad * 8];
        }
        for (int i = 0; i < 4; ++i)
            for (int j = 0; j < 4; ++j)
                acc[i][j] = __builtin_amdgcn_mfma_f32_16x16x32_bf16(af[i], bfr[j], acc[i][j], 0, 0, 0);
        __syncthreads();
    }

    for (int i = 0; i < 4; ++i)
        for (int j = 0; j < 4; ++j)
            for (int r = 0; r < 4; ++r) {
                int rg = bm * 128 + wm * 64 + i * 16 + quad * 4 + r;
                int cg = bn * 128 + wn * 64 + j * 16 + l16;
                size_t idx = (size_t)rg * N + cg;
                float v = acc[i][j][r];
                if (EPI == 0) {
                    ((float*)out)[idx] = v;
                } else if (EPI == 1) {
                    ((u16*)out)[idx] = f2bf(v);
                } else if (EPI == 2) {
                    float t = fmaxf(v, 0.f);
                    ((u16*)out)[idx] = f2bf(t * t);
                } else {
                    ((float*)out)[idx] = res[idx] + v;
                }
            }
}

// ---------------------------------------------------------------------------
// Flash attention, causal GQA. Q [B,T,NH,128] bf16, K/V [B,T,NKV,128] bf16.
// Block = (qtile of 64 rows, head, batch); 4 waves, 16 q-rows per wave.
// ---------------------------------------------------------------------------
__launch_bounds__(256, 2)
__global__ void flash_attn(const u16* __restrict__ Q, const u16* __restrict__ Kb,
                           const u16* __restrict__ Vb, u16* __restrict__ Y) {
    __shared__ __attribute__((aligned(16))) u16 Qs[64 * 128];
    __shared__ __attribute__((aligned(16))) u16 Ks[64 * 128];
    __shared__ __attribute__((aligned(16))) u16 Vst[128 * 64];   // [d][key]
    __shared__ __attribute__((aligned(16))) u16 Ps[4][16 * 64];  // per wave

    int qt = blockIdx.x, h = blockIdx.y, b = blockIdx.z;
    int kvh = h >> 2;                       // NH/NKV = 4
    int tid = threadIdx.x, lane = tid & 63, wave = tid >> 6;
    int quad = lane >> 4, l16 = lane & 15;
    int q0 = qt * 64;

    {   // stage Q tile once
        int r = lane >> 4;
        int c = (lane & 15) * 8;
        for (int ci = 0; ci < 4; ++ci) {
            int row = wave * 16 + ci * 4 + r;
            const u16* g = Q + ((size_t)((b * T_ + q0 + row) * NH_ + h)) * HD_ + c;
            load_lds16(g, &Qs[(wave * 16 + ci * 4) * 128]);
        }
    }

    float m_i[4], l_i[4];
    f32x4 zero = {0.f, 0.f, 0.f, 0.f};
    f32x4 o[8];
    for (int t = 0; t < 8; ++t) o[t] = zero;
    for (int r = 0; r < 4; ++r) { m_i[r] = -__builtin_inff(); l_i[r] = 0.f; }
    const float scale = 0.08838834764831845f;   // 1/sqrt(128)

    int nkt = qt + 1;
    for (int kt = 0; kt < nkt; ++kt) {
        __syncthreads();   // prior tile fully consumed (and Q staging drained)
        {   // stage K tile (global_load_lds)
            int r = lane >> 4;
            int c = (lane & 15) * 8;
            for (int ci = 0; ci < 4; ++ci) {
                int row = wave * 16 + ci * 4 + r;
                const u16* g = Kb + ((size_t)((b * T_ + kt * 64 + row) * NKV_ + kvh)) * HD_ + c;
                load_lds16(g, &Ks[(wave * 16 + ci * 4) * 128]);
            }
        }
        // stage V transposed via registers
        for (int i = 0; i < 4; ++i) {
            int chunk = i * 256 + tid;          // 0..1023
            int row = chunk >> 4;               // key 0..63
            int c8  = (chunk & 15) * 8;
            u16x8 vv = *(const u16x8*)(Vb + ((size_t)((b * T_ + kt * 64 + row) * NKV_ + kvh)) * HD_ + c8);
            for (int j = 0; j < 8; ++j) Vst[(c8 + j) * 64 + row] = vv[j];
        }
        __syncthreads();

        // S = Q K^T for this wave's 16 rows, 4 tiles of 16 keys
        f32x4 s[4];
        for (int tn = 0; tn < 4; ++tn) {
            f32x4 z = zero;
            for (int ks = 0; ks < 4; ++ks) {
                bf16x8 a  = *(const bf16x8*)&Qs[(wave * 16 + l16) * 128 + ks * 32 + quad * 8];
                bf16x8 bb = *(const bf16x8*)&Ks[(tn * 16 + l16) * 128 + ks * 32 + quad * 8];
                z = __builtin_amdgcn_mfma_f32_16x16x32_bf16(a, bb, z, 0, 0, 0);
            }
            s[tn] = z;
        }

        // online softmax (rows = quad*4+r, cols = tn*16+l16)
        int kbase = kt * 64;
        float p[4][4], mrow[4];
        for (int r = 0; r < 4; ++r) {
            int qg = q0 + wave * 16 + quad * 4 + r;
            float mx = -__builtin_inff();
            for (int tn = 0; tn < 4; ++tn) {
                int kg = kbase + tn * 16 + l16;
                float sc = s[tn][r] * scale;
                if (kg > qg) sc = -__builtin_inff();
                p[tn][r] = sc;
                mx = fmaxf(mx, sc);
            }
            mrow[r] = mx;
        }
        for (int r = 0; r < 4; ++r) {
            float mx = mrow[r];
            mx = fmaxf(mx, __shfl_xor(mx, 1, 64));
            mx = fmaxf(mx, __shfl_xor(mx, 2, 64));
            mx = fmaxf(mx, __shfl_xor(mx, 4, 64));
            mx = fmaxf(mx, __shfl_xor(mx, 8, 64));
            mrow[r] = mx;
        }
        float alpha[4];
        for (int r = 0; r < 4; ++r) {
            float mnew = fmaxf(m_i[r], mrow[r]);
            alpha[r] = __expf(m_i[r] - mnew);    // first tile: exp(-inf)=0
            m_i[r] = mnew;
            float sum = 0.f;
            for (int tn = 0; tn < 4; ++tn) {
                float e = __expf(p[tn][r] - mnew);
                p[tn][r] = e;
                sum += e;
            }
            sum += __shfl_xor(sum, 1, 64);
            sum += __shfl_xor(sum, 2, 64);
            sum += __shfl_xor(sum, 4, 64);
            sum += __shfl_xor(sum, 8, 64);
            l_i[r] = l_i[r] * alpha[r] + sum;
        }
        for (int t = 0; t < 8; ++t)
            for (int r = 0; r < 4; ++r) o[t][r] *= alpha[r];

        // P (C-layout) -> LDS -> A-layout (guide m120 pattern; wave-local)
        for (int r = 0; r < 4; ++r)
            for (int tn = 0; tn < 4; ++tn)
                Ps[wave][(quad * 4 + r) * 64 + tn * 16 + l16] = f2bf(p[tn][r]);

        for (int ks = 0; ks < 2; ++ks) {
            bf16x8 pa = *(const bf16x8*)&Ps[wave][l16 * 64 + ks * 32 + quad * 8];
            for (int t = 0; t < 8; ++t) {
                bf16x8 vb8 = *(const bf16x8*)&Vst[(t * 16 + l16) * 64 + ks * 32 + quad * 8];
                o[t] = __builtin_amdgcn_mfma_f32_16x16x32_bf16(pa, vb8, o[t], 0, 0, 0);
            }
        }
    }

    for (int r = 0; r < 4; ++r) {
        float inv = 1.0f / l_i[r];
        int qg = q0 + wave * 16 + quad * 4 + r;
        u16* yr = Y + ((size_t)((b * T_ + qg) * NH_ + h)) * HD_;
        for (int t = 0; t < 8; ++t)
            yr[t * 16 + l16] = f2bf(o[t][r] * inv);
    }
}

// ---------------------------------------------------------------------------
extern "C" void kernel_launch(void* const* d_in, const int* in_sizes, int n_in,
                              void* d_out, int out_size, void* d_ws, size_t ws_size,
                              hipStream_t stream) {
    const float* x     = (const float*)d_in[0];
    const float* cosb  = (const float*)d_in[1];
    const float* sinb  = (const float*)d_in[2];
    const float* wq    = (const float*)d_in[3];
    const float* wk    = (const float*)d_in[4];
    const float* wv    = (const float*)d_in[5];
    const float* wo    = (const float*)d_in[6];
    const float* wfc   = (const float*)d_in[7];
    const float* wproj = (const float*)d_in[8];

    char* ws = (char*)d_ws;
    size_t off = 0;
    auto alloc = [&](size_t bytes) { char* p = ws + off; off += (bytes + 255) & ~(size_t)255; return p; };

    u16*   wqT    = (u16*)alloc((size_t)C_ * C_ * 2);          // [2048][2048]
    u16*   wkT    = (u16*)alloc((size_t)NKV_ * HD_ * C_ * 2);  // [512][2048]
    u16*   wvT    = (u16*)alloc((size_t)NKV_ * HD_ * C_ * 2);
    u16*   woT    = (u16*)alloc((size_t)C_ * C_ * 2);
    u16*   wfcT   = (u16*)alloc((size_t)DFF_ * C_ * 2);        // [8192][2048]
    u16*   wprojT = (u16*)alloc((size_t)C_ * DFF_ * 2);        // [2048][8192]
    u16*   hbuf   = (u16*)alloc((size_t)B_ * T_ * C_ * 2);     // rmsnorm out (reused for h2)
    float* x2     = (float*)alloc((size_t)B_ * T_ * C_ * 4);   // post-attn residual
    u16*   ybuf   = (u16*)alloc((size_t)B_ * T_ * C_ * 2);     // attention out
    char*  scratch = ws + off;                                  // 64 MB reuse region
    float* q_tmp  = (float*)alloc((size_t)B_ * T_ * C_ * 4);
    float* k_tmp  = (float*)alloc((size_t)B_ * T_ * NKV_ * HD_ * 4);
    u16*   qb     = (u16*)alloc((size_t)B_ * T_ * C_ * 2);
    u16*   kb     = (u16*)alloc((size_t)B_ * T_ * NKV_ * HD_ * 2);
    u16*   vb     = (u16*)alloc((size_t)B_ * T_ * NKV_ * HD_ * 2);
    u16*   ffbuf  = (u16*)scratch;                             // [4096][8192] bf16, reuses qkv scratch

    const int M = B_ * T_;   // 4096
    dim3 tb(256);

    // 1. weights -> bf16 [N][K]
    transpose_cast<<<dim3(C_ / 32,   C_ / 32),  tb, 0, stream>>>(wq,    wqT,    C_,   C_);
    transpose_cast<<<dim3(512 / 32,  C_ / 32),  tb, 0, stream>>>(wk,    wkT,    C_,   512);
    transpose_cast<<<dim3(512 / 32,  C_ / 32),  tb, 0, stream>>>(wv,    wvT,    C_,   512);
    transpose_cast<<<dim3(C_ / 32,   C_ / 32),  tb, 0, stream>>>(wo,    woT,    C_,   C_);
    transpose_cast<<<dim3(DFF_ / 32, C_ / 32),  tb, 0, stream>>>(wfc,   wfcT,   C_,   DFF_);
    transpose_cast<<<dim3(C_ / 32,   DFF_ / 32), tb, 0, stream>>>(wproj, wprojT, DFF_, C_);

    // 2. h = rmsnorm(x)
    rmsnorm_rows<<<M, tb, 0, stream>>>(x, hbuf);

    // 3. q/k/v projections
    gemm_bt<0><<<dim3(C_ / 128,  M / 128), tb, 0, stream>>>(hbuf, wqT, q_tmp, nullptr, M, C_,  C_);
    gemm_bt<0><<<dim3(512 / 128, M / 128), tb, 0, stream>>>(hbuf, wkT, k_tmp, nullptr, M, 512, C_);
    gemm_bt<1><<<dim3(512 / 128, M / 128), tb, 0, stream>>>(hbuf, wvT, vb,    nullptr, M, 512, C_);

    // 4. RoPE + qk-rmsnorm
    rope_rms<<<(B_ * T_ * NH_) / 4,  tb, 0, stream>>>(q_tmp, cosb, sinb, qb, NH_);
    rope_rms<<<(B_ * T_ * NKV_) / 4, tb, 0, stream>>>(k_tmp, cosb, sinb, kb, NKV_);

    // 5. causal GQA flash attention
    flash_attn<<<dim3(T_ / 64, NH_, B_), tb, 0, stream>>>(qb, kb, vb, ybuf);

    // 6. x2 = x + y @ wo
    gemm_bt<3><<<dim3(C_ / 128, M / 128), tb, 0, stream>>>(ybuf, woT, x2, x, M, C_, C_);

    // 7. h2 = rmsnorm(x2)
    rmsnorm_rows<<<M, tb, 0, stream>>>(x2, hbuf);

    // 8. ff = relu(h2 @ w_fc)^2
    gemm_bt<2><<<dim3(DFF_ / 128, M / 128), tb, 0, stream>>>(hbuf, wfcT, ffbuf, nullptr, M, DFF_, C_);

    // 9. out = x2 + ff @ w_proj
    gemm_bt<3><<<dim3(C_ / 128, M / 128), tb, 0, stream>>>(ffbuf, wprojT, d_out, x2, M, C_, DFF_);
}

// Round 2
// 938.945 us; speedup vs baseline: 1.4303x; 1.4303x over previous
//
#include <hip/hip_runtime.h>
#include <cstdint>
#include <cstddef>

// ---------------------------------------------------------------------------
// Transformer block, B=2 T=2048 C=2048 NH=16 NKV=4 HD=128 DFF=8192, gfx950.
// R1: rewrite flash attention — S^T orientation (both MFMA operands from
// natural row-major LDS), global V pre-transpose, vectorized P handoff,
// 128-row Q tiles, LDS reuse (Qs slice -> per-wave P buffer), 64KB LDS.
// ---------------------------------------------------------------------------

#define B_    2
#define T_    2048
#define C_    2048
#define NH_   16
#define NKV_  4
#define HD_   128
#define DFF_  8192
#define EPS_  1.1920928955078125e-07f   // jnp.finfo(float32).eps

typedef short          bf16x8 __attribute__((ext_vector_type(8)));
typedef float          f32x4  __attribute__((ext_vector_type(4)));
typedef unsigned short u16;
typedef unsigned short u16x8  __attribute__((ext_vector_type(8)));
typedef unsigned short u16x4  __attribute__((ext_vector_type(4)));

__device__ __forceinline__ u16 f2bf(float f) {
    unsigned u = __float_as_uint(f);
    unsigned r = u + 0x7fffu + ((u >> 16) & 1u);   // RNE; inputs are finite
    return (u16)(r >> 16);
}

__device__ __forceinline__ void load_lds16(const void* g, void* l) {
    // 16B per lane, LDS dest = wave-uniform base + lane*16 (guide §5 caveat)
    __builtin_amdgcn_global_load_lds(
        (__attribute__((address_space(1))) void*)(g),
        (__attribute__((address_space(3))) void*)(l), 16, 0, 0);
}

// ---------------------------------------------------------------------------
// Weight transpose + cast: src [K][N] f32  ->  dst [N][K] bf16
// ---------------------------------------------------------------------------
__global__ void transpose_cast(const float* __restrict__ src, u16* __restrict__ dst,
                               int K, int N) {
    __shared__ float tile[32][33];
    int tx = threadIdx.x & 31;
    int ty = threadIdx.x >> 5;            // 0..7
    int n0 = blockIdx.x * 32;
    int k0 = blockIdx.y * 32;
    for (int j = 0; j < 4; ++j)
        tile[ty + j * 8][tx] = src[(size_t)(k0 + ty + j * 8) * N + n0 + tx];
    __syncthreads();
    for (int j = 0; j < 4; ++j)
        dst[(size_t)(n0 + ty + j * 8) * K + k0 + tx] = f2bf(tile[tx][ty + j * 8]);
}

// ---------------------------------------------------------------------------
// V transpose: vb [B][T][NKV][HD] bf16 -> Vt [B][NKV][HD][T] bf16
// Reads coalesced (64 consecutive d per wave); writes u16x8 per thread.
// ---------------------------------------------------------------------------
__global__ void transpose_v(const u16* __restrict__ vb, u16* __restrict__ Vt) {
    int bx   = blockIdx.x;           // 64 t-chunks * 2 d-blocks
    int dblk = bx & 1;
    int t0   = (bx >> 1) * 32;
    int kvh  = blockIdx.y, b = blockIdx.z;
    int dl   = threadIdx.x & 63;
    int tc   = threadIdx.x >> 6;     // 0..3
    int d    = dblk * 64 + dl;
    u16x8 v8;
    for (int j = 0; j < 8; ++j) {
        int t = t0 + tc * 8 + j;
        v8[j] = vb[((size_t)(b * T_ + t) * NKV_ + kvh) * HD_ + d];
    }
    *(u16x8*)(Vt + ((size_t)((b * NKV_ + kvh) * HD_ + d)) * T_ + t0 + tc * 8) = v8;
}

// ---------------------------------------------------------------------------
// RMSNorm over rows of [M][2048] f32 -> bf16
// ---------------------------------------------------------------------------
__global__ void rmsnorm_rows(const float* __restrict__ x, u16* __restrict__ out) {
    int row = blockIdx.x;
    const float4* xr = (const float4*)(x + (size_t)row * C_);
    float4 a = xr[threadIdx.x];
    float4 b = xr[threadIdx.x + 256];
    float ss = a.x * a.x + a.y * a.y + a.z * a.z + a.w * a.w
             + b.x * b.x + b.y * b.y + b.z * b.z + b.w * b.w;
    for (int m = 1; m < 64; m <<= 1) ss += __shfl_xor(ss, m, 64);
    __shared__ float part[4];
    if ((threadIdx.x & 63) == 0) part[threadIdx.x >> 6] = ss;
    __syncthreads();
    float tot = part[0] + part[1] + part[2] + part[3];
    float sc = rsqrtf(tot * (1.0f / C_) + EPS_);
    u16x4 o1, o2;
    o1[0] = f2bf(a.x * sc); o1[1] = f2bf(a.y * sc); o1[2] = f2bf(a.z * sc); o1[3] = f2bf(a.w * sc);
    o2[0] = f2bf(b.x * sc); o2[1] = f2bf(b.y * sc); o2[2] = f2bf(b.z * sc); o2[3] = f2bf(b.w * sc);
    u16x4* orow = (u16x4*)(out + (size_t)row * C_);
    orow[threadIdx.x]       = o1;
    orow[threadIdx.x + 256] = o2;
}

// ---------------------------------------------------------------------------
// RoPE + per-head RMSNorm: X f32 [B,T,nh,128] -> Out bf16. One wave per row.
// ---------------------------------------------------------------------------
__global__ void rope_rms(const float* __restrict__ X, const float* __restrict__ cosb,
                         const float* __restrict__ sinb, u16* __restrict__ Out,
                         int nheads) {
    int wid  = (int)((blockIdx.x * blockDim.x + threadIdx.x) >> 6);
    int lane = threadIdx.x & 63;
    int t = (wid / nheads) % T_;
    size_t base = (size_t)wid * HD_;
    float x1 = X[base + lane];
    float x2 = X[base + 64 + lane];
    float c  = cosb[t * 64 + lane];
    float sn = sinb[t * 64 + lane];
    float r1 = x1 * c + x2 * sn;
    float r2 = x2 * c - x1 * sn;
    float ss = r1 * r1 + r2 * r2;
    for (int m = 1; m < 64; m <<= 1) ss += __shfl_xor(ss, m, 64);
    float sc = rsqrtf(ss * (1.0f / HD_) + EPS_);
    Out[base + lane]      = f2bf(r1 * sc);
    Out[base + 64 + lane] = f2bf(r2 * sc);
}

// ---------------------------------------------------------------------------
// GEMM: C[M][N] = A[M][K](bf16) * Bt[N][K](bf16)^T, 128x128x32 tile, m97-style.
// EPI: 0=store f32, 1=store bf16, 2=relu^2 -> bf16, 3=residual(f32)+ -> f32
// ---------------------------------------------------------------------------
template <int EPI>
__launch_bounds__(256, 2)
__global__ void gemm_bt(const u16* __restrict__ A, const u16* __restrict__ Bt,
                        void* __restrict__ out, const float* __restrict__ res,
                        int M, int N, int K) {
    __shared__ __attribute__((aligned(16))) u16 As[128 * 32];
    __shared__ __attribute__((aligned(16))) u16 Bs[128 * 32];
    int tid  = threadIdx.x;
    int lane = tid & 63;
    int wave = tid >> 6;
    int quad = lane >> 4;
    int l16  = lane & 15;
    int bn = blockIdx.x, bm = blockIdx.y;
    int wm = wave >> 1, wn = wave & 1;

    int srow = lane >> 2;          // 0..15
    int scol = (lane & 3) * 8;     // 0,8,16,24
    const u16* Ag = A  + (size_t)(bm * 128 + wave * 32 + srow) * K + scol;
    const u16* Bg = Bt + (size_t)(bn * 128 + wave * 32 + srow) * K + scol;
    u16* Asw = &As[(wave * 32) * 32];
    u16* Bsw = &Bs[(wave * 32) * 32];

    f32x4 zero = {0.f, 0.f, 0.f, 0.f};
    f32x4 acc[4][4];
    for (int i = 0; i < 4; ++i)
        for (int j = 0; j < 4; ++j) acc[i][j] = zero;

    for (int k0 = 0; k0 < K; k0 += 32) {
        load_lds16(Ag + k0,                  Asw);
        load_lds16(Ag + k0 + (size_t)16 * K, Asw + 16 * 32);
        load_lds16(Bg + k0,                  Bsw);
        load_lds16(Bg + k0 + (size_t)16 * K, Bsw + 16 * 32);
        __syncthreads();
        bf16x8 af[4], bfr[4];
        for (int t = 0; t < 4; ++t) {
            af[t]  = *(const bf16x8*)&As[(wm * 64 + t * 16 + l16) * 32 + quad * 8];
            bfr[t] = *(const bf16x8*)&Bs[(wn * 64 + t * 16 + l16) * 32 + quad * 8];
        }
        for (int i = 0; i < 4; ++i)
            for (int j = 0; j < 4; ++j)
                acc[i][j] = __builtin_amdgcn_mfma_f32_16x16x32_bf16(af[i], bfr[j], acc[i][j], 0, 0, 0);
        __syncthreads();
    }

    for (int i = 0; i < 4; ++i)
        for (int j = 0; j < 4; ++j)
            for (int r = 0; r < 4; ++r) {
                int rg = bm * 128 + wm * 64 + i * 16 + quad * 4 + r;
                int cg = bn * 128 + wn * 64 + j * 16 + l16;
                size_t idx = (size_t)rg * N + cg;
                float v = acc[i][j][r];
                if (EPI == 0) {
                    ((float*)out)[idx] = v;
                } else if (EPI == 1) {
                    ((u16*)out)[idx] = f2bf(v);
                } else if (EPI == 2) {
                    float t = fmaxf(v, 0.f);
                    ((u16*)out)[idx] = f2bf(t * t);
                } else {
                    ((float*)out)[idx] = res[idx] + v;
                }
            }
}

// ---------------------------------------------------------------------------
// Flash attention v2, causal GQA.
// Q [B,T,NH,128] bf16, K [B,T,NKV,128] bf16, Vt [B,NKV,128,T] bf16.
// Block: 128 Q-rows, 4 waves x 32 rows. K-tile 64. S^T = K*Q^T so both
// MFMA operands read natural row-major LDS. P handoff: ds_write_b64 into
// padded (stride 72) per-wave buffer carved out of the dead Qs slice.
// LDS = 32K(Qs) + 16K(Ks) + 16K(Vs) = 64KB -> 2 blocks/CU.
// ---------------------------------------------------------------------------
__launch_bounds__(256, 2)
__global__ void flash_attn2(const u16* __restrict__ Q, const u16* __restrict__ Kb,
                            const u16* __restrict__ Vt, u16* __restrict__ Y) {
    __shared__ __attribute__((aligned(16))) u16 Qs[128 * 128];
    __shared__ __attribute__((aligned(16))) u16 Ks[64 * 128];
    __shared__ __attribute__((aligned(16))) u16 Vs[128 * 64];

    // triangle-balanced decode: pair qt with 15-qt across grid halves
    int bid = blockIdx.x;
    int half = bid >> 8, idx = bid & 255;
    int qr = idx & 15;
    int qt = half ? (15 - qr) : qr;
    int bh = (idx >> 4) | (half << 4);
    int b = bh >> 4, h = bh & 15;
    int kvh = h >> 2;
    int q0 = qt * 128;

    int tid = threadIdx.x, lane = tid & 63, wave = tid >> 6;
    int quad = lane >> 4, l16 = lane & 15;

    {   // stage this wave's 32 Q rows
        int r = lane >> 4, cc = (lane & 15) * 8;
        for (int c = 0; c < 8; ++c) {
            int row = wave * 32 + c * 4 + r;
            const u16* g = Q + ((size_t)((b * T_ + q0 + row) * NH_ + h)) * HD_ + cc;
            load_lds16(g, &Qs[(wave * 32 + c * 4) * 128]);
        }
    }
    __syncthreads();

    // preload Q fragments (B-operand: lane l16 = q-row, quad*8.. = d)
    bf16x8 qf[2][4];
    for (int qtile = 0; qtile < 2; ++qtile)
        for (int kd = 0; kd < 4; ++kd)
            qf[qtile][kd] = *(const bf16x8*)&Qs[(wave * 32 + qtile * 16 + l16) * 128 + kd * 32 + quad * 8];
    // Qs slice of this wave is now dead -> reuse as P buffer [32 q][stride 72]
    u16* Ps = &Qs[wave * 32 * 128];

    f32x4 zero = {0.f, 0.f, 0.f, 0.f};
    f32x4 o[2][8];
    for (int qtile = 0; qtile < 2; ++qtile)
        for (int dt = 0; dt < 8; ++dt) o[qtile][dt] = zero;
    float m_i[2] = {-__builtin_inff(), -__builtin_inff()};
    float l_i[2] = {0.f, 0.f};
    const float s2s = 0.08838834764831845f * 1.4426950408889634f;  // scale*log2e

    int nkt = 2 * qt + 2;
    for (int kt = 0; kt < nkt; ++kt) {
        __syncthreads();   // prior Ks/Vs fully consumed by all waves
        {   // stage K: 16 rows per wave, natural [key][d]
            int cc = (lane & 15) * 8;
            for (int c = 0; c < 4; ++c) {
                int row = wave * 16 + c * 4 + (lane >> 4);
                const u16* g = Kb + ((size_t)((b * T_ + kt * 64 + row) * NKV_ + kvh)) * HD_ + cc;
                load_lds16(g, &Ks[(wave * 16 + c * 4) * 128]);
            }
        }
        {   // stage V^T: 32 d-rows per wave from Vt, [d][key]
            int kc = (lane & 7) * 8;
            for (int c = 0; c < 4; ++c) {
                int drow = wave * 32 + c * 8 + (lane >> 3);
                const u16* g = Vt + ((size_t)((b * NKV_ + kvh) * HD_ + drow)) * T_ + kt * 64 + kc;
                load_lds16(g, &Vs[(wave * 32 + c * 8) * 64]);
            }
        }
        __syncthreads();

        // S^T[key][q]: A = K rows, B = Q rows. Result: col(l16)=q, row(quad*4+r)=key
        f32x4 st[2][4];
        for (int qtile = 0; qtile < 2; ++qtile)
            for (int tn = 0; tn < 4; ++tn) st[qtile][tn] = zero;
        for (int tn = 0; tn < 4; ++tn)
            for (int kd = 0; kd < 4; ++kd) {
                bf16x8 kf = *(const bf16x8*)&Ks[(tn * 16 + l16) * 128 + kd * 32 + quad * 8];
                st[0][tn] = __builtin_amdgcn_mfma_f32_16x16x32_bf16(kf, qf[0][kd], st[0][tn], 0, 0, 0);
                st[1][tn] = __builtin_amdgcn_mfma_f32_16x16x32_bf16(kf, qf[1][kd], st[1][tn], 0, 0, 0);
            }

        // online softmax per qtile; lane's column q = l16 (state replicated over quads)
        for (int qtile = 0; qtile < 2; ++qtile) {
            int qmin = q0 + wave * 32 + qtile * 16;
            int qg   = qmin + l16;
            bool need_mask = (kt * 64 + 63 > qmin);
            float mx = -__builtin_inff();
            for (int tn = 0; tn < 4; ++tn)
                for (int r = 0; r < 4; ++r) {
                    float v = st[qtile][tn][r] * s2s;
                    if (need_mask) {
                        int key = kt * 64 + tn * 16 + quad * 4 + r;
                        if (key > qg) v = -__builtin_inff();
                    }
                    st[qtile][tn][r] = v;
                    mx = fmaxf(mx, v);
                }
            mx = fmaxf(mx, __shfl_xor(mx, 16, 64));
            mx = fmaxf(mx, __shfl_xor(mx, 32, 64));
            float mnew = fmaxf(m_i[qtile], mx);
            float al   = exp2f(m_i[qtile] - mnew);       // -inf first tile -> 0
            m_i[qtile] = mnew;
            float sum = 0.f;
            for (int tn = 0; tn < 4; ++tn) {
                u16x4 pk;
                for (int r = 0; r < 4; ++r) {
                    float e = exp2f(st[qtile][tn][r] - mnew);
                    sum += e;
                    pk[r] = f2bf(e);
                }
                // P[q][key]: row q = qtile*16+l16, keys quad*4+..  (b64, ~2-way banks)
                *(u16x4*)&Ps[(qtile * 16 + l16) * 72 + tn * 16 + quad * 4] = pk;
            }
            sum += __shfl_xor(sum, 16, 64);
            sum += __shfl_xor(sum, 32, 64);
            l_i[qtile] = l_i[qtile] * al + sum;
            // rescale O (rows q = quad*4+r need alpha from lane quad*4+r)
            float aB[4];
            for (int r = 0; r < 4; ++r) aB[r] = __shfl(al, quad * 4 + r, 64);
            for (int dt = 0; dt < 8; ++dt)
                for (int r = 0; r < 4; ++r) o[qtile][dt][r] *= aB[r];
        }

        // PV: A = P rows (m=q), B = V^T rows (n=d). Vs frags shared across qtiles.
        bf16x8 pf[2][2];
        for (int qtile = 0; qtile < 2; ++qtile)
            for (int ks = 0; ks < 2; ++ks)
                pf[qtile][ks] = *(const bf16x8*)&Ps[(qtile * 16 + l16) * 72 + ks * 32 + quad * 8];
        for (int ks = 0; ks < 2; ++ks)
            for (int dt = 0; dt < 8; ++dt) {
                bf16x8 vf = *(const bf16x8*)&Vs[(dt * 16 + l16) * 64 + ks * 32 + quad * 8];
                o[0][dt] = __builtin_amdgcn_mfma_f32_16x16x32_bf16(pf[0][ks], vf, o[0][dt], 0, 0, 0);
                o[1][dt] = __builtin_amdgcn_mfma_f32_16x16x32_bf16(pf[1][ks], vf, o[1][dt], 0, 0, 0);
            }
    }

    // epilogue: O rows q = quad*4+r, cols d = dt*16+l16
    for (int qtile = 0; qtile < 2; ++qtile) {
        float inv = 1.0f / l_i[qtile];
        float iB[4];
        for (int r = 0; r < 4; ++r) iB[r] = __shfl(inv, quad * 4 + r, 64);
        for (int r = 0; r < 4; ++r) {
            int qg = q0 + wave * 32 + qtile * 16 + quad * 4 + r;
            u16* yr = Y + ((size_t)((b * T_ + qg) * NH_ + h)) * HD_;
            for (int dt = 0; dt < 8; ++dt)
                yr[dt * 16 + l16] = f2bf(o[qtile][dt][r] * iB[r]);
        }
    }
}

// ---------------------------------------------------------------------------
extern "C" void kernel_launch(void* const* d_in, const int* in_sizes, int n_in,
                              void* d_out, int out_size, void* d_ws, size_t ws_size,
                              hipStream_t stream) {
    const float* x     = (const float*)d_in[0];
    const float* cosb  = (const float*)d_in[1];
    const float* sinb  = (const float*)d_in[2];
    const float* wq    = (const float*)d_in[3];
    const float* wk    = (const float*)d_in[4];
    const float* wv    = (const float*)d_in[5];
    const float* wo    = (const float*)d_in[6];
    const float* wfc   = (const float*)d_in[7];
    const float* wproj = (const float*)d_in[8];

    char* ws = (char*)d_ws;
    size_t off = 0;
    auto alloc = [&](size_t bytes) { char* p = ws + off; off += (bytes + 255) & ~(size_t)255; return p; };

    u16*   wqT    = (u16*)alloc((size_t)C_ * C_ * 2);          // [2048][2048]
    u16*   wkT    = (u16*)alloc((size_t)NKV_ * HD_ * C_ * 2);  // [512][2048]
    u16*   wvT    = (u16*)alloc((size_t)NKV_ * HD_ * C_ * 2);
    u16*   woT    = (u16*)alloc((size_t)C_ * C_ * 2);
    u16*   wfcT   = (u16*)alloc((size_t)DFF_ * C_ * 2);        // [8192][2048]
    u16*   wprojT = (u16*)alloc((size_t)C_ * DFF_ * 2);        // [2048][8192]
    u16*   hbuf   = (u16*)alloc((size_t)B_ * T_ * C_ * 2);     // rmsnorm out (reused for h2)
    float* x2     = (float*)alloc((size_t)B_ * T_ * C_ * 4);   // post-attn residual
    u16*   ybuf   = (u16*)alloc((size_t)B_ * T_ * C_ * 2);     // attention out
    u16*   Vtb    = (u16*)alloc((size_t)B_ * NKV_ * HD_ * T_ * 2);  // V transposed
    // 64MB scratch region: qkv temporaries, later reused by ffbuf
    char*  scratch = alloc((size_t)B_ * T_ * DFF_ * 2);        // 64MB
    float* q_tmp  = (float*)scratch;                                     // 32MB
    float* k_tmp  = (float*)(scratch + (size_t)B_ * T_ * C_ * 4);        // 8MB
    u16*   qb     = (u16*)(scratch + (size_t)B_ * T_ * C_ * 4 + (size_t)B_ * T_ * 512 * 4);
    u16*   kb     = (u16*)((char*)qb + (size_t)B_ * T_ * C_ * 2);
    u16*   vb     = (u16*)((char*)kb + (size_t)B_ * T_ * 512 * 2);
    u16*   ffbuf  = (u16*)scratch;                             // [4096][8192] bf16

    const int M = B_ * T_;   // 4096
    dim3 tb(256);

    // 1. weights -> bf16 [N][K]
    transpose_cast<<<dim3(C_ / 32,   C_ / 32),  tb, 0, stream>>>(wq,    wqT,    C_,   C_);
    transpose_cast<<<dim3(512 / 32,  C_ / 32),  tb, 0, stream>>>(wk,    wkT,    C_,   512);
    transpose_cast<<<dim3(512 / 32,  C_ / 32),  tb, 0, stream>>>(wv,    wvT,    C_,   512);
    transpose_cast<<<dim3(C_ / 32,   C_ / 32),  tb, 0, stream>>>(wo,    woT,    C_,   C_);
    transpose_cast<<<dim3(DFF_ / 32, C_ / 32),  tb, 0, stream>>>(wfc,   wfcT,   C_,   DFF_);
    transpose_cast<<<dim3(C_ / 32,   DFF_ / 32), tb, 0, stream>>>(wproj, wprojT, DFF_, C_);

    // 2. h = rmsnorm(x)
    rmsnorm_rows<<<M, tb, 0, stream>>>(x, hbuf);

    // 3. q/k/v projections
    gemm_bt<0><<<dim3(C_ / 128,  M / 128), tb, 0, stream>>>(hbuf, wqT, q_tmp, nullptr, M, C_,  C_);
    gemm_bt<0><<<dim3(512 / 128, M / 128), tb, 0, stream>>>(hbuf, wkT, k_tmp, nullptr, M, 512, C_);
    gemm_bt<1><<<dim3(512 / 128, M / 128), tb, 0, stream>>>(hbuf, wvT, vb,    nullptr, M, 512, C_);

    // 4. RoPE + qk-rmsnorm; V global transpose
    rope_rms<<<(B_ * T_ * NH_) / 4,  tb, 0, stream>>>(q_tmp, cosb, sinb, qb, NH_);
    rope_rms<<<(B_ * T_ * NKV_) / 4, tb, 0, stream>>>(k_tmp, cosb, sinb, kb, NKV_);
    transpose_v<<<dim3(128, NKV_, B_), tb, 0, stream>>>(vb, Vtb);

    // 5. causal GQA flash attention (512 blocks, 2/CU)
    flash_attn2<<<dim3(512), tb, 0, stream>>>(qb, kb, Vtb, ybuf);

    // 6. x2 = x + y @ wo
    gemm_bt<3><<<dim3(C_ / 128, M / 128), tb, 0, stream>>>(ybuf, woT, x2, x, M, C_, C_);

    // 7. h2 = rmsnorm(x2)
    rmsnorm_rows<<<M, tb, 0, stream>>>(x2, hbuf);

    // 8. ff = relu(h2 @ w_fc)^2   (ffbuf reuses the qkv scratch region)
    gemm_bt<2><<<dim3(DFF_ / 128, M / 128), tb, 0, stream>>>(hbuf, wfcT, ffbuf, nullptr, M, DFF_, C_);

    // 9. out = x2 + ff @ w_proj
    gemm_bt<3><<<dim3(C_ / 128, M / 128), tb, 0, stream>>>(ffbuf, wprojT, d_out, x2, M, C_, DFF_);
}

// Round 3
// 857.117 us; speedup vs baseline: 1.5669x; 1.0955x over previous
//
#include <hip/hip_runtime.h>
#include <cstdint>
#include <cstddef>

// ---------------------------------------------------------------------------
// Transformer block, B=2 T=2048 C=2048 NH=16 NKV=4 HD=128 DFF=8192, gfx950.
// R2: software-pipelined (double-buffered) GEMM K-loop — prefetch next tile
// after the single per-iter barrier so the global_load_lds DMA overlaps the
// 64-MFMA compute phase. Fused QKV projection (N=3072, 768 blocks = 3/CU).
// ---------------------------------------------------------------------------

#define B_    2
#define T_    2048
#define C_    2048
#define NH_   16
#define NKV_  4
#define HD_   128
#define DFF_  8192
#define EPS_  1.1920928955078125e-07f   // jnp.finfo(float32).eps

typedef short          bf16x8 __attribute__((ext_vector_type(8)));
typedef float          f32x4  __attribute__((ext_vector_type(4)));
typedef unsigned short u16;
typedef unsigned short u16x8  __attribute__((ext_vector_type(8)));
typedef unsigned short u16x4  __attribute__((ext_vector_type(4)));

__device__ __forceinline__ u16 f2bf(float f) {
    unsigned u = __float_as_uint(f);
    unsigned r = u + 0x7fffu + ((u >> 16) & 1u);   // RNE; inputs are finite
    return (u16)(r >> 16);
}

__device__ __forceinline__ void load_lds16(const void* g, void* l) {
    // 16B per lane, LDS dest = wave-uniform base + lane*16 (guide §5 caveat)
    __builtin_amdgcn_global_load_lds(
        (__attribute__((address_space(1))) void*)(g),
        (__attribute__((address_space(3))) void*)(l), 16, 0, 0);
}

// ---------------------------------------------------------------------------
// Weight transpose + cast: src [K][N] f32  ->  dst [N][K] bf16
// ---------------------------------------------------------------------------
__global__ void transpose_cast(const float* __restrict__ src, u16* __restrict__ dst,
                               int K, int N) {
    __shared__ float tile[32][33];
    int tx = threadIdx.x & 31;
    int ty = threadIdx.x >> 5;            // 0..7
    int n0 = blockIdx.x * 32;
    int k0 = blockIdx.y * 32;
    for (int j = 0; j < 4; ++j)
        tile[ty + j * 8][tx] = src[(size_t)(k0 + ty + j * 8) * N + n0 + tx];
    __syncthreads();
    for (int j = 0; j < 4; ++j)
        dst[(size_t)(n0 + ty + j * 8) * K + k0 + tx] = f2bf(tile[tx][ty + j * 8]);
}

// ---------------------------------------------------------------------------
// V transpose: vb [B][T][NKV][HD] bf16 -> Vt [B][NKV][HD][T] bf16
// ---------------------------------------------------------------------------
__global__ void transpose_v(const u16* __restrict__ vb, u16* __restrict__ Vt) {
    int bx   = blockIdx.x;           // 64 t-chunks * 2 d-blocks
    int dblk = bx & 1;
    int t0   = (bx >> 1) * 32;
    int kvh  = blockIdx.y, b = blockIdx.z;
    int dl   = threadIdx.x & 63;
    int tc   = threadIdx.x >> 6;     // 0..3
    int d    = dblk * 64 + dl;
    u16x8 v8;
    for (int j = 0; j < 8; ++j) {
        int t = t0 + tc * 8 + j;
        v8[j] = vb[((size_t)(b * T_ + t) * NKV_ + kvh) * HD_ + d];
    }
    *(u16x8*)(Vt + ((size_t)((b * NKV_ + kvh) * HD_ + d)) * T_ + t0 + tc * 8) = v8;
}

// ---------------------------------------------------------------------------
// RMSNorm over rows of [M][2048] f32 -> bf16
// ---------------------------------------------------------------------------
__global__ void rmsnorm_rows(const float* __restrict__ x, u16* __restrict__ out) {
    int row = blockIdx.x;
    const float4* xr = (const float4*)(x + (size_t)row * C_);
    float4 a = xr[threadIdx.x];
    float4 b = xr[threadIdx.x + 256];
    float ss = a.x * a.x + a.y * a.y + a.z * a.z + a.w * a.w
             + b.x * b.x + b.y * b.y + b.z * b.z + b.w * b.w;
    for (int m = 1; m < 64; m <<= 1) ss += __shfl_xor(ss, m, 64);
    __shared__ float part[4];
    if ((threadIdx.x & 63) == 0) part[threadIdx.x >> 6] = ss;
    __syncthreads();
    float tot = part[0] + part[1] + part[2] + part[3];
    float sc = rsqrtf(tot * (1.0f / C_) + EPS_);
    u16x4 o1, o2;
    o1[0] = f2bf(a.x * sc); o1[1] = f2bf(a.y * sc); o1[2] = f2bf(a.z * sc); o1[3] = f2bf(a.w * sc);
    o2[0] = f2bf(b.x * sc); o2[1] = f2bf(b.y * sc); o2[2] = f2bf(b.z * sc); o2[3] = f2bf(b.w * sc);
    u16x4* orow = (u16x4*)(out + (size_t)row * C_);
    orow[threadIdx.x]       = o1;
    orow[threadIdx.x + 256] = o2;
}

// ---------------------------------------------------------------------------
// RoPE + per-head RMSNorm: X f32 [B,T,nh,128] -> Out bf16. One wave per row.
// ---------------------------------------------------------------------------
__global__ void rope_rms(const float* __restrict__ X, const float* __restrict__ cosb,
                         const float* __restrict__ sinb, u16* __restrict__ Out,
                         int nheads) {
    int wid  = (int)((blockIdx.x * blockDim.x + threadIdx.x) >> 6);
    int lane = threadIdx.x & 63;
    int t = (wid / nheads) % T_;
    size_t base = (size_t)wid * HD_;
    float x1 = X[base + lane];
    float x2 = X[base + 64 + lane];
    float c  = cosb[t * 64 + lane];
    float sn = sinb[t * 64 + lane];
    float r1 = x1 * c + x2 * sn;
    float r2 = x2 * c - x1 * sn;
    float ss = r1 * r1 + r2 * r2;
    for (int m = 1; m < 64; m <<= 1) ss += __shfl_xor(ss, m, 64);
    float sc = rsqrtf(ss * (1.0f / HD_) + EPS_);
    Out[base + lane]      = f2bf(r1 * sc);
    Out[base + 64 + lane] = f2bf(r2 * sc);
}

// ---------------------------------------------------------------------------
// Pipelined GEMM: C[M][N] = A[M][K](bf16) * Bt[N][K](bf16)^T, 128x128 tile,
// double-buffered 32-wide K-steps, ONE barrier per step, prefetch overlaps
// the 64-MFMA compute phase.
// EPI: 0=f32, 1=bf16, 2=relu^2->bf16, 3=res(f32)+ -> f32,
//      4=qkv routing (cols 0..2047 f32 q | 2048..2559 f32 k | 2560..3071 bf16 v)
// ---------------------------------------------------------------------------
template <int EPI>
__launch_bounds__(256, 2)
__global__ void gemm_bt(const u16* __restrict__ A, const u16* __restrict__ Bt,
                        void* __restrict__ out, const float* __restrict__ res,
                        void* __restrict__ out2, void* __restrict__ out3,
                        int M, int N, int K) {
    __shared__ __attribute__((aligned(16))) u16 As[2][128 * 32];
    __shared__ __attribute__((aligned(16))) u16 Bs[2][128 * 32];
    int tid  = threadIdx.x;
    int lane = tid & 63;
    int wave = tid >> 6;
    int quad = lane >> 4;
    int l16  = lane & 15;
    int bn = blockIdx.x, bm = blockIdx.y;
    int wm = wave >> 1, wn = wave & 1;

    int srow = lane >> 2;          // 0..15
    int scol = (lane & 3) * 8;     // 0,8,16,24
    const u16* Ag = A  + (size_t)(bm * 128 + wave * 32 + srow) * K + scol;
    const u16* Bg = Bt + (size_t)(bn * 128 + wave * 32 + srow) * K + scol;

    auto stage = [&](int kk, int buf) {
        u16* Ab = &As[buf][(wave * 32) * 32];
        u16* Bb = &Bs[buf][(wave * 32) * 32];
        load_lds16(Ag + kk,                  Ab);
        load_lds16(Ag + kk + (size_t)16 * K, Ab + 16 * 32);
        load_lds16(Bg + kk,                  Bb);
        load_lds16(Bg + kk + (size_t)16 * K, Bb + 16 * 32);
    };

    f32x4 zero = {0.f, 0.f, 0.f, 0.f};
    f32x4 acc[4][4];
    for (int i = 0; i < 4; ++i)
        for (int j = 0; j < 4; ++j) acc[i][j] = zero;

    stage(0, 0);                               // prefetch tile 0
    int cur = 0;
    for (int k0 = 0; k0 < K; k0 += 32, cur ^= 1) {
        __syncthreads();                       // tile k landed; prev compute done
        if (k0 + 32 < K) stage(k0 + 32, cur ^ 1);   // overlaps compute below
        bf16x8 af[4], bfr[4];
        for (int t = 0; t < 4; ++t) {
            af[t]  = *(const bf16x8*)&As[cur][(wm * 64 + t * 16 + l16) * 32 + quad * 8];
            bfr[t] = *(const bf16x8*)&Bs[cur][(wn * 64 + t * 16 + l16) * 32 + quad * 8];
        }
        for (int i = 0; i < 4; ++i)
            for (int j = 0; j < 4; ++j)
                acc[i][j] = __builtin_amdgcn_mfma_f32_16x16x32_bf16(af[i], bfr[j], acc[i][j], 0, 0, 0);
    }

    for (int i = 0; i < 4; ++i)
        for (int j = 0; j < 4; ++j)
            for (int r = 0; r < 4; ++r) {
                int rg = bm * 128 + wm * 64 + i * 16 + quad * 4 + r;
                int cg = bn * 128 + wn * 64 + j * 16 + l16;
                float v = acc[i][j][r];
                if (EPI == 0) {
                    ((float*)out)[(size_t)rg * N + cg] = v;
                } else if (EPI == 1) {
                    ((u16*)out)[(size_t)rg * N + cg] = f2bf(v);
                } else if (EPI == 2) {
                    float t = fmaxf(v, 0.f);
                    ((u16*)out)[(size_t)rg * N + cg] = f2bf(t * t);
                } else if (EPI == 3) {
                    size_t idx = (size_t)rg * N + cg;
                    ((float*)out)[idx] = res[idx] + v;
                } else {                        // EPI 4: fused qkv routing
                    if (cg < 2048)      ((float*)out)[(size_t)rg * 2048 + cg] = v;
                    else if (cg < 2560) ((float*)out2)[(size_t)rg * 512 + (cg - 2048)] = v;
                    else                ((u16*)out3)[(size_t)rg * 512 + (cg - 2560)] = f2bf(v);
                }
            }
}

// ---------------------------------------------------------------------------
// Flash attention v2, causal GQA.  (unchanged from R1 — see R1 notes)
// ---------------------------------------------------------------------------
__launch_bounds__(256, 2)
__global__ void flash_attn2(const u16* __restrict__ Q, const u16* __restrict__ Kb,
                            const u16* __restrict__ Vt, u16* __restrict__ Y) {
    __shared__ __attribute__((aligned(16))) u16 Qs[128 * 128];
    __shared__ __attribute__((aligned(16))) u16 Ks[64 * 128];
    __shared__ __attribute__((aligned(16))) u16 Vs[128 * 64];

    int bid = blockIdx.x;
    int half = bid >> 8, idx = bid & 255;
    int qr = idx & 15;
    int qt = half ? (15 - qr) : qr;
    int bh = (idx >> 4) | (half << 4);
    int b = bh >> 4, h = bh & 15;
    int kvh = h >> 2;
    int q0 = qt * 128;

    int tid = threadIdx.x, lane = tid & 63, wave = tid >> 6;
    int quad = lane >> 4, l16 = lane & 15;

    {   // stage this wave's 32 Q rows
        int r = lane >> 4, cc = (lane & 15) * 8;
        for (int c = 0; c < 8; ++c) {
            int row = wave * 32 + c * 4 + r;
            const u16* g = Q + ((size_t)((b * T_ + q0 + row) * NH_ + h)) * HD_ + cc;
            load_lds16(g, &Qs[(wave * 32 + c * 4) * 128]);
        }
    }
    __syncthreads();

    bf16x8 qf[2][4];
    for (int qtile = 0; qtile < 2; ++qtile)
        for (int kd = 0; kd < 4; ++kd)
            qf[qtile][kd] = *(const bf16x8*)&Qs[(wave * 32 + qtile * 16 + l16) * 128 + kd * 32 + quad * 8];
    u16* Ps = &Qs[wave * 32 * 128];   // dead Qs slice -> P buffer [32][72]

    f32x4 zero = {0.f, 0.f, 0.f, 0.f};
    f32x4 o[2][8];
    for (int qtile = 0; qtile < 2; ++qtile)
        for (int dt = 0; dt < 8; ++dt) o[qtile][dt] = zero;
    float m_i[2] = {-__builtin_inff(), -__builtin_inff()};
    float l_i[2] = {0.f, 0.f};
    const float s2s = 0.08838834764831845f * 1.4426950408889634f;  // scale*log2e

    int nkt = 2 * qt + 2;
    for (int kt = 0; kt < nkt; ++kt) {
        __syncthreads();
        {   // stage K: 16 rows per wave
            int cc = (lane & 15) * 8;
            for (int c = 0; c < 4; ++c) {
                int row = wave * 16 + c * 4 + (lane >> 4);
                const u16* g = Kb + ((size_t)((b * T_ + kt * 64 + row) * NKV_ + kvh)) * HD_ + cc;
                load_lds16(g, &Ks[(wave * 16 + c * 4) * 128]);
            }
        }
        {   // stage V^T: 32 d-rows per wave
            int kc = (lane & 7) * 8;
            for (int c = 0; c < 4; ++c) {
                int drow = wave * 32 + c * 8 + (lane >> 3);
                const u16* g = Vt + ((size_t)((b * NKV_ + kvh) * HD_ + drow)) * T_ + kt * 64 + kc;
                load_lds16(g, &Vs[(wave * 32 + c * 8) * 64]);
            }
        }
        __syncthreads();

        f32x4 st[2][4];
        for (int qtile = 0; qtile < 2; ++qtile)
            for (int tn = 0; tn < 4; ++tn) st[qtile][tn] = zero;
        for (int tn = 0; tn < 4; ++tn)
            for (int kd = 0; kd < 4; ++kd) {
                bf16x8 kf = *(const bf16x8*)&Ks[(tn * 16 + l16) * 128 + kd * 32 + quad * 8];
                st[0][tn] = __builtin_amdgcn_mfma_f32_16x16x32_bf16(kf, qf[0][kd], st[0][tn], 0, 0, 0);
                st[1][tn] = __builtin_amdgcn_mfma_f32_16x16x32_bf16(kf, qf[1][kd], st[1][tn], 0, 0, 0);
            }

        for (int qtile = 0; qtile < 2; ++qtile) {
            int qmin = q0 + wave * 32 + qtile * 16;
            int qg   = qmin + l16;
            bool need_mask = (kt * 64 + 63 > qmin);
            float mx = -__builtin_inff();
            for (int tn = 0; tn < 4; ++tn)
                for (int r = 0; r < 4; ++r) {
                    float v = st[qtile][tn][r] * s2s;
                    if (need_mask) {
                        int key = kt * 64 + tn * 16 + quad * 4 + r;
                        if (key > qg) v = -__builtin_inff();
                    }
                    st[qtile][tn][r] = v;
                    mx = fmaxf(mx, v);
                }
            mx = fmaxf(mx, __shfl_xor(mx, 16, 64));
            mx = fmaxf(mx, __shfl_xor(mx, 32, 64));
            float mnew = fmaxf(m_i[qtile], mx);
            float al   = exp2f(m_i[qtile] - mnew);
            m_i[qtile] = mnew;
            float sum = 0.f;
            for (int tn = 0; tn < 4; ++tn) {
                u16x4 pk;
                for (int r = 0; r < 4; ++r) {
                    float e = exp2f(st[qtile][tn][r] - mnew);
                    sum += e;
                    pk[r] = f2bf(e);
                }
                *(u16x4*)&Ps[(qtile * 16 + l16) * 72 + tn * 16 + quad * 4] = pk;
            }
            sum += __shfl_xor(sum, 16, 64);
            sum += __shfl_xor(sum, 32, 64);
            l_i[qtile] = l_i[qtile] * al + sum;
            float aB[4];
            for (int r = 0; r < 4; ++r) aB[r] = __shfl(al, quad * 4 + r, 64);
            for (int dt = 0; dt < 8; ++dt)
                for (int r = 0; r < 4; ++r) o[qtile][dt][r] *= aB[r];
        }

        bf16x8 pf[2][2];
        for (int qtile = 0; qtile < 2; ++qtile)
            for (int ks = 0; ks < 2; ++ks)
                pf[qtile][ks] = *(const bf16x8*)&Ps[(qtile * 16 + l16) * 72 + ks * 32 + quad * 8];
        for (int ks = 0; ks < 2; ++ks)
            for (int dt = 0; dt < 8; ++dt) {
                bf16x8 vf = *(const bf16x8*)&Vs[(dt * 16 + l16) * 64 + ks * 32 + quad * 8];
                o[0][dt] = __builtin_amdgcn_mfma_f32_16x16x32_bf16(pf[0][ks], vf, o[0][dt], 0, 0, 0);
                o[1][dt] = __builtin_amdgcn_mfma_f32_16x16x32_bf16(pf[1][ks], vf, o[1][dt], 0, 0, 0);
            }
    }

    for (int qtile = 0; qtile < 2; ++qtile) {
        float inv = 1.0f / l_i[qtile];
        float iB[4];
        for (int r = 0; r < 4; ++r) iB[r] = __shfl(inv, quad * 4 + r, 64);
        for (int r = 0; r < 4; ++r) {
            int qg = q0 + wave * 32 + qtile * 16 + quad * 4 + r;
            u16* yr = Y + ((size_t)((b * T_ + qg) * NH_ + h)) * HD_;
            for (int dt = 0; dt < 8; ++dt)
                yr[dt * 16 + l16] = f2bf(o[qtile][dt][r] * iB[r]);
        }
    }
}

// ---------------------------------------------------------------------------
extern "C" void kernel_launch(void* const* d_in, const int* in_sizes, int n_in,
                              void* d_out, int out_size, void* d_ws, size_t ws_size,
                              hipStream_t stream) {
    const float* x     = (const float*)d_in[0];
    const float* cosb  = (const float*)d_in[1];
    const float* sinb  = (const float*)d_in[2];
    const float* wq    = (const float*)d_in[3];
    const float* wk    = (const float*)d_in[4];
    const float* wv    = (const float*)d_in[5];
    const float* wo    = (const float*)d_in[6];
    const float* wfc   = (const float*)d_in[7];
    const float* wproj = (const float*)d_in[8];

    char* ws = (char*)d_ws;
    size_t off = 0;
    auto alloc = [&](size_t bytes) { char* p = ws + off; off += (bytes + 255) & ~(size_t)255; return p; };

    u16*   wqkvT  = (u16*)alloc((size_t)3072 * C_ * 2);        // rows: q 0..2047 | k ..2559 | v ..3071
    u16*   woT    = (u16*)alloc((size_t)C_ * C_ * 2);
    u16*   wfcT   = (u16*)alloc((size_t)DFF_ * C_ * 2);        // [8192][2048]
    u16*   wprojT = (u16*)alloc((size_t)C_ * DFF_ * 2);        // [2048][8192]
    u16*   hbuf   = (u16*)alloc((size_t)B_ * T_ * C_ * 2);     // rmsnorm out (reused for h2)
    float* x2     = (float*)alloc((size_t)B_ * T_ * C_ * 4);   // post-attn residual
    u16*   ybuf   = (u16*)alloc((size_t)B_ * T_ * C_ * 2);     // attention out
    u16*   Vtb    = (u16*)alloc((size_t)B_ * NKV_ * HD_ * T_ * 2);  // V transposed
    // 64MB scratch region: qkv temporaries, later reused by ffbuf
    char*  scratch = alloc((size_t)B_ * T_ * DFF_ * 2);        // 64MB
    float* q_tmp  = (float*)scratch;                                     // 32MB
    float* k_tmp  = (float*)(scratch + (size_t)B_ * T_ * C_ * 4);        // 8MB
    u16*   qb     = (u16*)(scratch + (size_t)B_ * T_ * C_ * 4 + (size_t)B_ * T_ * 512 * 4);
    u16*   kb     = (u16*)((char*)qb + (size_t)B_ * T_ * C_ * 2);
    u16*   vb     = (u16*)((char*)kb + (size_t)B_ * T_ * 512 * 2);
    u16*   ffbuf  = (u16*)scratch;                             // [4096][8192] bf16

    const int M = B_ * T_;   // 4096
    dim3 tb(256);

    // 1. weights -> bf16 [N][K]; q/k/v packed into one [3072][2048] buffer
    transpose_cast<<<dim3(C_ / 32,   C_ / 32),  tb, 0, stream>>>(wq,    wqkvT,               C_,   C_);
    transpose_cast<<<dim3(512 / 32,  C_ / 32),  tb, 0, stream>>>(wk,    wqkvT + (size_t)2048 * C_, C_, 512);
    transpose_cast<<<dim3(512 / 32,  C_ / 32),  tb, 0, stream>>>(wv,    wqkvT + (size_t)2560 * C_, C_, 512);
    transpose_cast<<<dim3(C_ / 32,   C_ / 32),  tb, 0, stream>>>(wo,    woT,    C_,   C_);
    transpose_cast<<<dim3(DFF_ / 32, C_ / 32),  tb, 0, stream>>>(wfc,   wfcT,   C_,   DFF_);
    transpose_cast<<<dim3(C_ / 32,   DFF_ / 32), tb, 0, stream>>>(wproj, wprojT, DFF_, C_);

    // 2. h = rmsnorm(x)
    rmsnorm_rows<<<M, tb, 0, stream>>>(x, hbuf);

    // 3. fused q/k/v projection (N=3072, 768 blocks = 3/CU)
    gemm_bt<4><<<dim3(3072 / 128, M / 128), tb, 0, stream>>>(hbuf, wqkvT, q_tmp, nullptr, k_tmp, vb, M, 3072, C_);

    // 4. RoPE + qk-rmsnorm; V global transpose
    rope_rms<<<(B_ * T_ * NH_) / 4,  tb, 0, stream>>>(q_tmp, cosb, sinb, qb, NH_);
    rope_rms<<<(B_ * T_ * NKV_) / 4, tb, 0, stream>>>(k_tmp, cosb, sinb, kb, NKV_);
    transpose_v<<<dim3(128, NKV_, B_), tb, 0, stream>>>(vb, Vtb);

    // 5. causal GQA flash attention (512 blocks, 2/CU)
    flash_attn2<<<dim3(512), tb, 0, stream>>>(qb, kb, Vtb, ybuf);

    // 6. x2 = x + y @ wo
    gemm_bt<3><<<dim3(C_ / 128, M / 128), tb, 0, stream>>>(ybuf, woT, x2, x, nullptr, nullptr, M, C_, C_);

    // 7. h2 = rmsnorm(x2)
    rmsnorm_rows<<<M, tb, 0, stream>>>(x2, hbuf);

    // 8. ff = relu(h2 @ w_fc)^2   (ffbuf reuses the qkv scratch region)
    gemm_bt<2><<<dim3(DFF_ / 128, M / 128), tb, 0, stream>>>(hbuf, wfcT, ffbuf, nullptr, nullptr, nullptr, M, DFF_, C_);

    // 9. out = x2 + ff @ w_proj
    gemm_bt<3><<<dim3(C_ / 128, M / 128), tb, 0, stream>>>(ffbuf, wprojT, d_out, x2, nullptr, nullptr, M, C_, DFF_);
}

// Round 4
// 834.722 us; speedup vs baseline: 1.6089x; 1.0268x over previous
//
#include <hip/hip_runtime.h>
#include <cstdint>
#include <cstddef>

// ---------------------------------------------------------------------------
// Transformer block, B=2 T=2048 C=2048 NH=16 NKV=4 HD=128 DFF=8192, gfx950.
// R3: XOR-swizzled LDS layouts (conflict kill) in gemm_bt (8way->4way) and
// flash_attn2 (16way->2way). Swizzle is applied on the GLOBAL source chunk a
// lane requests, since global_load_lds always writes lane*16 contiguously.
// Also: 6 transpose_cast launches -> 1; 2 rope launches -> 1.
// ---------------------------------------------------------------------------

#define B_    2
#define T_    2048
#define C_    2048
#define NH_   16
#define NKV_  4
#define HD_   128
#define DFF_  8192
#define EPS_  1.1920928955078125e-07f   // jnp.finfo(float32).eps

typedef short          bf16x8 __attribute__((ext_vector_type(8)));
typedef float          f32x4  __attribute__((ext_vector_type(4)));
typedef unsigned short u16;
typedef unsigned short u16x8  __attribute__((ext_vector_type(8)));
typedef unsigned short u16x4  __attribute__((ext_vector_type(4)));

__device__ __forceinline__ u16 f2bf(float f) {
    unsigned u = __float_as_uint(f);
    unsigned r = u + 0x7fffu + ((u >> 16) & 1u);   // RNE; inputs are finite
    return (u16)(r >> 16);
}

__device__ __forceinline__ void load_lds16(const void* g, void* l) {
    // 16B per lane, LDS dest = wave-uniform base + lane*16 (guide §5 caveat)
    __builtin_amdgcn_global_load_lds(
        (__attribute__((address_space(1))) void*)(g),
        (__attribute__((address_space(3))) void*)(l), 16, 0, 0);
}

// ---------------------------------------------------------------------------
// Batched weight transpose+cast: 6 weights in one launch.
// Each src [K][N] f32 -> dst [N][K] bf16.
// ---------------------------------------------------------------------------
struct TD  { const float* src; u16* dst; int K, N, boff; };
struct TD6 { TD t[6]; };

__global__ void transpose_cast_all(TD6 d) {
    int bid = blockIdx.x;
    int di = 0;
    for (int i = 5; i > 0; --i) if (bid >= d.t[i].boff) { di = i; break; }
    const float* src = d.t[di].src;
    u16* dst = d.t[di].dst;
    int K = d.t[di].K, N = d.t[di].N;
    int lb = bid - d.t[di].boff;
    int nx = N >> 5;
    int n0 = (lb % nx) * 32;
    int k0 = (lb / nx) * 32;

    __shared__ float tile[32][33];
    int tx = threadIdx.x & 31;
    int ty = threadIdx.x >> 5;            // 0..7
    for (int j = 0; j < 4; ++j)
        tile[ty + j * 8][tx] = src[(size_t)(k0 + ty + j * 8) * N + n0 + tx];
    __syncthreads();
    for (int j = 0; j < 4; ++j)
        dst[(size_t)(n0 + ty + j * 8) * K + k0 + tx] = f2bf(tile[tx][ty + j * 8]);
}

// ---------------------------------------------------------------------------
// V transpose: vb [B][T][NKV][HD] bf16 -> Vt [B][NKV][HD][T] bf16
// ---------------------------------------------------------------------------
__global__ void transpose_v(const u16* __restrict__ vb, u16* __restrict__ Vt) {
    int bx   = blockIdx.x;           // 64 t-chunks * 2 d-blocks
    int dblk = bx & 1;
    int t0   = (bx >> 1) * 32;
    int kvh  = blockIdx.y, b = blockIdx.z;
    int dl   = threadIdx.x & 63;
    int tc   = threadIdx.x >> 6;     // 0..3
    int d    = dblk * 64 + dl;
    u16x8 v8;
    for (int j = 0; j < 8; ++j) {
        int t = t0 + tc * 8 + j;
        v8[j] = vb[((size_t)(b * T_ + t) * NKV_ + kvh) * HD_ + d];
    }
    *(u16x8*)(Vt + ((size_t)((b * NKV_ + kvh) * HD_ + d)) * T_ + t0 + tc * 8) = v8;
}

// ---------------------------------------------------------------------------
// RMSNorm over rows of [M][2048] f32 -> bf16
// ---------------------------------------------------------------------------
__global__ void rmsnorm_rows(const float* __restrict__ x, u16* __restrict__ out) {
    int row = blockIdx.x;
    const float4* xr = (const float4*)(x + (size_t)row * C_);
    float4 a = xr[threadIdx.x];
    float4 b = xr[threadIdx.x + 256];
    float ss = a.x * a.x + a.y * a.y + a.z * a.z + a.w * a.w
             + b.x * b.x + b.y * b.y + b.z * b.z + b.w * b.w;
    for (int m = 1; m < 64; m <<= 1) ss += __shfl_xor(ss, m, 64);
    __shared__ float part[4];
    if ((threadIdx.x & 63) == 0) part[threadIdx.x >> 6] = ss;
    __syncthreads();
    float tot = part[0] + part[1] + part[2] + part[3];
    float sc = rsqrtf(tot * (1.0f / C_) + EPS_);
    u16x4 o1, o2;
    o1[0] = f2bf(a.x * sc); o1[1] = f2bf(a.y * sc); o1[2] = f2bf(a.z * sc); o1[3] = f2bf(a.w * sc);
    o2[0] = f2bf(b.x * sc); o2[1] = f2bf(b.y * sc); o2[2] = f2bf(b.z * sc); o2[3] = f2bf(b.w * sc);
    u16x4* orow = (u16x4*)(out + (size_t)row * C_);
    orow[threadIdx.x]       = o1;
    orow[threadIdx.x + 256] = o2;
}

// ---------------------------------------------------------------------------
// RoPE + per-head RMSNorm for BOTH q and k in one launch. One wave per row.
// ---------------------------------------------------------------------------
__global__ void rope_rms2(const float* __restrict__ Xq, const float* __restrict__ Xk,
                          const float* __restrict__ cosb, const float* __restrict__ sinb,
                          u16* __restrict__ Oq, u16* __restrict__ Ok) {
    int gw   = (int)((blockIdx.x * blockDim.x + threadIdx.x) >> 6);
    int lane = threadIdx.x & 63;
    const float* X; u16* O; int t;
    if (gw < B_ * T_ * NH_) {
        X = Xq + (size_t)gw * HD_;  O = Oq + (size_t)gw * HD_;  t = (gw / NH_) % T_;
    } else {
        int w2 = gw - B_ * T_ * NH_;
        X = Xk + (size_t)w2 * HD_;  O = Ok + (size_t)w2 * HD_;  t = (w2 / NKV_) % T_;
    }
    float x1 = X[lane];
    float x2 = X[64 + lane];
    float c  = cosb[t * 64 + lane];
    float sn = sinb[t * 64 + lane];
    float r1 = x1 * c + x2 * sn;
    float r2 = x2 * c - x1 * sn;
    float ss = r1 * r1 + r2 * r2;
    for (int m = 1; m < 64; m <<= 1) ss += __shfl_xor(ss, m, 64);
    float sc = rsqrtf(ss * (1.0f / HD_) + EPS_);
    O[lane]      = f2bf(r1 * sc);
    O[64 + lane] = f2bf(r2 * sc);
}

// ---------------------------------------------------------------------------
// Pipelined GEMM: C[M][N] = A[M][K](bf16) * Bt[N][K](bf16)^T, 128x128 tile,
// double-buffered, one barrier/step. LDS tiles XOR-swizzled: LDS slot
// (row, c) holds global chunk c^(row&3)  (chunk = 16B = 8 bf16).
// EPI: 0=f32, 1=bf16, 2=relu^2->bf16, 3=res(f32)+ -> f32,
//      4=qkv routing (cols 0..2047 f32 q | 2048..2559 f32 k | 2560..3071 bf16 v)
// ---------------------------------------------------------------------------
template <int EPI>
__launch_bounds__(256, 2)
__global__ void gemm_bt(const u16* __restrict__ A, const u16* __restrict__ Bt,
                        void* __restrict__ out, const float* __restrict__ res,
                        void* __restrict__ out2, void* __restrict__ out3,
                        int M, int N, int K) {
    __shared__ __attribute__((aligned(16))) u16 As[2][128 * 32];
    __shared__ __attribute__((aligned(16))) u16 Bs[2][128 * 32];
    int tid  = threadIdx.x;
    int lane = tid & 63;
    int wave = tid >> 6;
    int quad = lane >> 4;
    int l16  = lane & 15;
    int bn = blockIdx.x, bm = blockIdx.y;
    int wm = wave >> 1, wn = wave & 1;

    int srow = lane >> 2;                                   // 0..15
    int scol = (((lane & 3) ^ (srow & 3)) ) * 8;            // swizzled source chunk
    const u16* Ag = A  + (size_t)(bm * 128 + wave * 32 + srow) * K + scol;
    const u16* Bg = Bt + (size_t)(bn * 128 + wave * 32 + srow) * K + scol;

    auto stage = [&](int kk, int buf) {
        u16* Ab = &As[buf][(wave * 32) * 32];
        u16* Bb = &Bs[buf][(wave * 32) * 32];
        load_lds16(Ag + kk,                  Ab);
        load_lds16(Ag + kk + (size_t)16 * K, Ab + 16 * 32);
        load_lds16(Bg + kk,                  Bb);
        load_lds16(Bg + kk + (size_t)16 * K, Bb + 16 * 32);
    };

    f32x4 zero = {0.f, 0.f, 0.f, 0.f};
    f32x4 acc[4][4];
    for (int i = 0; i < 4; ++i)
        for (int j = 0; j < 4; ++j) acc[i][j] = zero;

    int rsw = (l16 & 3);                                    // read-side swizzle key
    stage(0, 0);                                            // prefetch tile 0
    int cur = 0;
    for (int k0 = 0; k0 < K; k0 += 32, cur ^= 1) {
        __syncthreads();                                    // tile k landed
        if (k0 + 32 < K) stage(k0 + 32, cur ^ 1);           // overlaps compute
        bf16x8 af[4], bfr[4];
        int cs = (quad ^ rsw) * 8;
        for (int t = 0; t < 4; ++t) {
            af[t]  = *(const bf16x8*)&As[cur][(wm * 64 + t * 16 + l16) * 32 + cs];
            bfr[t] = *(const bf16x8*)&Bs[cur][(wn * 64 + t * 16 + l16) * 32 + cs];
        }
        for (int i = 0; i < 4; ++i)
            for (int j = 0; j < 4; ++j)
                acc[i][j] = __builtin_amdgcn_mfma_f32_16x16x32_bf16(af[i], bfr[j], acc[i][j], 0, 0, 0);
    }

    for (int i = 0; i < 4; ++i)
        for (int j = 0; j < 4; ++j)
            for (int r = 0; r < 4; ++r) {
                int rg = bm * 128 + wm * 64 + i * 16 + quad * 4 + r;
                int cg = bn * 128 + wn * 64 + j * 16 + l16;
                float v = acc[i][j][r];
                if (EPI == 0) {
                    ((float*)out)[(size_t)rg * N + cg] = v;
                } else if (EPI == 1) {
                    ((u16*)out)[(size_t)rg * N + cg] = f2bf(v);
                } else if (EPI == 2) {
                    float t = fmaxf(v, 0.f);
                    ((u16*)out)[(size_t)rg * N + cg] = f2bf(t * t);
                } else if (EPI == 3) {
                    size_t idx = (size_t)rg * N + cg;
                    ((float*)out)[idx] = res[idx] + v;
                } else {                        // EPI 4: fused qkv routing
                    if (cg < 2048)      ((float*)out)[(size_t)rg * 2048 + cg] = v;
                    else if (cg < 2560) ((float*)out2)[(size_t)rg * 512 + (cg - 2048)] = v;
                    else                ((u16*)out3)[(size_t)rg * 512 + (cg - 2560)] = f2bf(v);
                }
            }
}

// ---------------------------------------------------------------------------
// Flash attention v3, causal GQA. Swizzled LDS:
//   Qs/Ks [row][128]: slot c holds global chunk c^(row&15)  -> reads 2-way
//   Vs    [d][64]   : slot c holds global chunk c^(d&7)     -> reads 2-way
// ---------------------------------------------------------------------------
__launch_bounds__(256, 2)
__global__ void flash_attn2(const u16* __restrict__ Q, const u16* __restrict__ Kb,
                            const u16* __restrict__ Vt, u16* __restrict__ Y) {
    __shared__ __attribute__((aligned(16))) u16 Qs[128 * 128];
    __shared__ __attribute__((aligned(16))) u16 Ks[64 * 128];
    __shared__ __attribute__((aligned(16))) u16 Vs[128 * 64];

    int bid = blockIdx.x;
    int half = bid >> 8, idx = bid & 255;
    int qr = idx & 15;
    int qt = half ? (15 - qr) : qr;
    int bh = (idx >> 4) | (half << 4);
    int b = bh >> 4, h = bh & 15;
    int kvh = h >> 2;
    int q0 = qt * 128;

    int tid = threadIdx.x, lane = tid & 63, wave = tid >> 6;
    int quad = lane >> 4, l16 = lane & 15;

    {   // stage this wave's 32 Q rows (swizzled source chunk)
        int r = lane >> 4;
        for (int c = 0; c < 8; ++c) {
            int row = wave * 32 + c * 4 + r;
            int cc = ((lane & 15) ^ (row & 15)) * 8;
            const u16* g = Q + ((size_t)((b * T_ + q0 + row) * NH_ + h)) * HD_ + cc;
            load_lds16(g, &Qs[(wave * 32 + c * 4) * 128]);
        }
    }
    __syncthreads();

    // Q frags: row = wave*32+qtile*16+l16 (row&15 == l16), chunk kd*4+quad
    bf16x8 qf[2][4];
    for (int qtile = 0; qtile < 2; ++qtile)
        for (int kd = 0; kd < 4; ++kd)
            qf[qtile][kd] = *(const bf16x8*)&Qs[(wave * 32 + qtile * 16 + l16) * 128
                                               + (((kd * 4 + quad) ^ l16) * 8)];
    u16* Ps = &Qs[wave * 32 * 128];   // dead Qs slice -> P buffer [32][72]

    f32x4 zero = {0.f, 0.f, 0.f, 0.f};
    f32x4 o[2][8];
    for (int qtile = 0; qtile < 2; ++qtile)
        for (int dt = 0; dt < 8; ++dt) o[qtile][dt] = zero;
    float m_i[2] = {-__builtin_inff(), -__builtin_inff()};
    float l_i[2] = {0.f, 0.f};
    const float s2s = 0.08838834764831845f * 1.4426950408889634f;  // scale*log2e

    int nkt = 2 * qt + 2;
    for (int kt = 0; kt < nkt; ++kt) {
        __syncthreads();
        {   // stage K: 16 rows per wave, swizzled
            int r = lane >> 4;
            for (int c = 0; c < 4; ++c) {
                int row = wave * 16 + c * 4 + r;
                int cc = ((lane & 15) ^ (row & 15)) * 8;
                const u16* g = Kb + ((size_t)((b * T_ + kt * 64 + row) * NKV_ + kvh)) * HD_ + cc;
                load_lds16(g, &Ks[(wave * 16 + c * 4) * 128]);
            }
        }
        {   // stage V^T: 32 d-rows per wave, swizzled ((d&7) key)
            int dr = lane >> 3;                         // 0..7
            int kc = (((lane & 7) ^ dr) ) * 8;
            for (int c = 0; c < 4; ++c) {
                int drow = wave * 32 + c * 8 + dr;
                const u16* g = Vt + ((size_t)((b * NKV_ + kvh) * HD_ + drow)) * T_ + kt * 64 + kc;
                load_lds16(g, &Vs[(wave * 32 + c * 8) * 64]);
            }
        }
        __syncthreads();

        // S^T[key][q]: A = K rows (row&15 == l16), B = Q frags
        f32x4 st[2][4];
        for (int qtile = 0; qtile < 2; ++qtile)
            for (int tn = 0; tn < 4; ++tn) st[qtile][tn] = zero;
        for (int tn = 0; tn < 4; ++tn)
            for (int kd = 0; kd < 4; ++kd) {
                bf16x8 kf = *(const bf16x8*)&Ks[(tn * 16 + l16) * 128
                                                + (((kd * 4 + quad) ^ l16) * 8)];
                st[0][tn] = __builtin_amdgcn_mfma_f32_16x16x32_bf16(kf, qf[0][kd], st[0][tn], 0, 0, 0);
                st[1][tn] = __builtin_amdgcn_mfma_f32_16x16x32_bf16(kf, qf[1][kd], st[1][tn], 0, 0, 0);
            }

        for (int qtile = 0; qtile < 2; ++qtile) {
            int qmin = q0 + wave * 32 + qtile * 16;
            int qg   = qmin + l16;
            bool need_mask = (kt * 64 + 63 > qmin);
            float mx = -__builtin_inff();
            for (int tn = 0; tn < 4; ++tn)
                for (int r = 0; r < 4; ++r) {
                    float v = st[qtile][tn][r] * s2s;
                    if (need_mask) {
                        int key = kt * 64 + tn * 16 + quad * 4 + r;
                        if (key > qg) v = -__builtin_inff();
                    }
                    st[qtile][tn][r] = v;
                    mx = fmaxf(mx, v);
                }
            mx = fmaxf(mx, __shfl_xor(mx, 16, 64));
            mx = fmaxf(mx, __shfl_xor(mx, 32, 64));
            float mnew = fmaxf(m_i[qtile], mx);
            float al   = exp2f(m_i[qtile] - mnew);
            m_i[qtile] = mnew;
            float sum = 0.f;
            for (int tn = 0; tn < 4; ++tn) {
                u16x4 pk;
                for (int r = 0; r < 4; ++r) {
                    float e = exp2f(st[qtile][tn][r] - mnew);
                    sum += e;
                    pk[r] = f2bf(e);
                }
                *(u16x4*)&Ps[(qtile * 16 + l16) * 72 + tn * 16 + quad * 4] = pk;
            }
            sum += __shfl_xor(sum, 16, 64);
            sum += __shfl_xor(sum, 32, 64);
            l_i[qtile] = l_i[qtile] * al + sum;
            float aB[4];
            for (int r = 0; r < 4; ++r) aB[r] = __shfl(al, quad * 4 + r, 64);
            for (int dt = 0; dt < 8; ++dt)
                for (int r = 0; r < 4; ++r) o[qtile][dt][r] *= aB[r];
        }

        // PV: A = P rows (m=q), B = V^T rows (n=d, swizzled (d&7) key)
        bf16x8 pf[2][2];
        for (int qtile = 0; qtile < 2; ++qtile)
            for (int ks = 0; ks < 2; ++ks)
                pf[qtile][ks] = *(const bf16x8*)&Ps[(qtile * 16 + l16) * 72 + ks * 32 + quad * 8];
        for (int ks = 0; ks < 2; ++ks)
            for (int dt = 0; dt < 8; ++dt) {
                bf16x8 vf = *(const bf16x8*)&Vs[(dt * 16 + l16) * 64
                                                + (((ks * 4 + quad) ^ (l16 & 7)) * 8)];
                o[0][dt] = __builtin_amdgcn_mfma_f32_16x16x32_bf16(pf[0][ks], vf, o[0][dt], 0, 0, 0);
                o[1][dt] = __builtin_amdgcn_mfma_f32_16x16x32_bf16(pf[1][ks], vf, o[1][dt], 0, 0, 0);
            }
    }

    for (int qtile = 0; qtile < 2; ++qtile) {
        float inv = 1.0f / l_i[qtile];
        float iB[4];
        for (int r = 0; r < 4; ++r) iB[r] = __shfl(inv, quad * 4 + r, 64);
        for (int r = 0; r < 4; ++r) {
            int qg = q0 + wave * 32 + qtile * 16 + quad * 4 + r;
            u16* yr = Y + ((size_t)((b * T_ + qg) * NH_ + h)) * HD_;
            for (int dt = 0; dt < 8; ++dt)
                yr[dt * 16 + l16] = f2bf(o[qtile][dt][r] * iB[r]);
        }
    }
}

// ---------------------------------------------------------------------------
extern "C" void kernel_launch(void* const* d_in, const int* in_sizes, int n_in,
                              void* d_out, int out_size, void* d_ws, size_t ws_size,
                              hipStream_t stream) {
    const float* x     = (const float*)d_in[0];
    const float* cosb  = (const float*)d_in[1];
    const float* sinb  = (const float*)d_in[2];
    const float* wq    = (const float*)d_in[3];
    const float* wk    = (const float*)d_in[4];
    const float* wv    = (const float*)d_in[5];
    const float* wo    = (const float*)d_in[6];
    const float* wfc   = (const float*)d_in[7];
    const float* wproj = (const float*)d_in[8];

    char* ws = (char*)d_ws;
    size_t off = 0;
    auto alloc = [&](size_t bytes) { char* p = ws + off; off += (bytes + 255) & ~(size_t)255; return p; };

    u16*   wqkvT  = (u16*)alloc((size_t)3072 * C_ * 2);        // rows: q 0..2047 | k ..2559 | v ..3071
    u16*   woT    = (u16*)alloc((size_t)C_ * C_ * 2);
    u16*   wfcT   = (u16*)alloc((size_t)DFF_ * C_ * 2);        // [8192][2048]
    u16*   wprojT = (u16*)alloc((size_t)C_ * DFF_ * 2);        // [2048][8192]
    u16*   hbuf   = (u16*)alloc((size_t)B_ * T_ * C_ * 2);     // rmsnorm out (reused for h2)
    float* x2     = (float*)alloc((size_t)B_ * T_ * C_ * 4);   // post-attn residual
    u16*   ybuf   = (u16*)alloc((size_t)B_ * T_ * C_ * 2);     // attention out
    u16*   Vtb    = (u16*)alloc((size_t)B_ * NKV_ * HD_ * T_ * 2);  // V transposed
    // 64MB scratch region: qkv temporaries, later reused by ffbuf
    char*  scratch = alloc((size_t)B_ * T_ * DFF_ * 2);        // 64MB
    float* q_tmp  = (float*)scratch;                                     // 32MB
    float* k_tmp  = (float*)(scratch + (size_t)B_ * T_ * C_ * 4);        // 8MB
    u16*   qb     = (u16*)(scratch + (size_t)B_ * T_ * C_ * 4 + (size_t)B_ * T_ * 512 * 4);
    u16*   kb     = (u16*)((char*)qb + (size_t)B_ * T_ * C_ * 2);
    u16*   vb     = (u16*)((char*)kb + (size_t)B_ * T_ * 512 * 2);
    u16*   ffbuf  = (u16*)scratch;                             // [4096][8192] bf16

    const int M = B_ * T_;   // 4096
    dim3 tb(256);

    // 1. weights -> bf16 [N][K] in ONE launch; q/k/v packed into [3072][2048]
    TD6 td;
    td.t[0] = { wq,    wqkvT,                       C_,   C_,   0 };
    td.t[1] = { wk,    wqkvT + (size_t)2048 * C_,   C_,   512,  4096 };
    td.t[2] = { wv,    wqkvT + (size_t)2560 * C_,   C_,   512,  5120 };
    td.t[3] = { wo,    woT,                         C_,   C_,   6144 };
    td.t[4] = { wfc,   wfcT,                        C_,   DFF_, 10240 };
    td.t[5] = { wproj, wprojT,                      DFF_, C_,   26624 };
    transpose_cast_all<<<dim3(43008), tb, 0, stream>>>(td);

    // 2. h = rmsnorm(x)
    rmsnorm_rows<<<M, tb, 0, stream>>>(x, hbuf);

    // 3. fused q/k/v projection (N=3072, 768 blocks = 3/CU)
    gemm_bt<4><<<dim3(3072 / 128, M / 128), tb, 0, stream>>>(hbuf, wqkvT, q_tmp, nullptr, k_tmp, vb, M, 3072, C_);

    // 4. RoPE + qk-rmsnorm (q and k in one launch); V global transpose
    rope_rms2<<<dim3((B_ * T_ * (NH_ + NKV_)) / 4), tb, 0, stream>>>(q_tmp, k_tmp, cosb, sinb, qb, kb);
    transpose_v<<<dim3(128, NKV_, B_), tb, 0, stream>>>(vb, Vtb);

    // 5. causal GQA flash attention (512 blocks, 2/CU)
    flash_attn2<<<dim3(512), tb, 0, stream>>>(qb, kb, Vtb, ybuf);

    // 6. x2 = x + y @ wo
    gemm_bt<3><<<dim3(C_ / 128, M / 128), tb, 0, stream>>>(ybuf, woT, x2, x, nullptr, nullptr, M, C_, C_);

    // 7. h2 = rmsnorm(x2)
    rmsnorm_rows<<<M, tb, 0, stream>>>(x2, hbuf);

    // 8. ff = relu(h2 @ w_fc)^2   (ffbuf reuses the qkv scratch region)
    gemm_bt<2><<<dim3(DFF_ / 128, M / 128), tb, 0, stream>>>(hbuf, wfcT, ffbuf, nullptr, nullptr, nullptr, M, DFF_, C_);

    // 9. out = x2 + ff @ w_proj
    gemm_bt<3><<<dim3(C_ / 128, M / 128), tb, 0, stream>>>(ffbuf, wprojT, d_out, x2, nullptr, nullptr, M, C_, DFF_);
}

// Round 5
// 786.219 us; speedup vs baseline: 1.7082x; 1.0617x over previous
//
#include <hip/hip_runtime.h>
#include <cstdint>
#include <cstddef>

// ---------------------------------------------------------------------------
// Transformer block, B=2 T=2048 C=2048 NH=16 NKV=4 HD=128 DFF=8192, gfx950.
// R4: split-K=2 for the grid-starved GEMMs (wo, proj: 512 -> 1024 blocks =
// 4/CU) with bf16 partials into dead buffers; fused reduce+rmsnorm and final
// reduce epilogue kernels. (R3 note: SQ_LDS_BANK_CONFLICT saturates at 2^24 —
// do not trust it.)
// ---------------------------------------------------------------------------

#define B_    2
#define T_    2048
#define C_    2048
#define NH_   16
#define NKV_  4
#define HD_   128
#define DFF_  8192
#define EPS_  1.1920928955078125e-07f   // jnp.finfo(float32).eps

typedef short          bf16x8 __attribute__((ext_vector_type(8)));
typedef float          f32x4  __attribute__((ext_vector_type(4)));
typedef unsigned short u16;
typedef unsigned short u16x8  __attribute__((ext_vector_type(8)));
typedef unsigned short u16x4  __attribute__((ext_vector_type(4)));

__device__ __forceinline__ u16 f2bf(float f) {
    unsigned u = __float_as_uint(f);
    unsigned r = u + 0x7fffu + ((u >> 16) & 1u);   // RNE; inputs are finite
    return (u16)(r >> 16);
}
__device__ __forceinline__ float bf2f(u16 u) {
    return __uint_as_float((unsigned)u << 16);
}

__device__ __forceinline__ void load_lds16(const void* g, void* l) {
    // 16B per lane, LDS dest = wave-uniform base + lane*16 (guide §5 caveat)
    __builtin_amdgcn_global_load_lds(
        (__attribute__((address_space(1))) void*)(g),
        (__attribute__((address_space(3))) void*)(l), 16, 0, 0);
}

// ---------------------------------------------------------------------------
// Batched weight transpose+cast: 6 weights in one launch.
// ---------------------------------------------------------------------------
struct TD  { const float* src; u16* dst; int K, N, boff; };
struct TD6 { TD t[6]; };

__global__ void transpose_cast_all(TD6 d) {
    int bid = blockIdx.x;
    int di = 0;
    for (int i = 5; i > 0; --i) if (bid >= d.t[i].boff) { di = i; break; }
    const float* src = d.t[di].src;
    u16* dst = d.t[di].dst;
    int K = d.t[di].K, N = d.t[di].N;
    int lb = bid - d.t[di].boff;
    int nx = N >> 5;
    int n0 = (lb % nx) * 32;
    int k0 = (lb / nx) * 32;

    __shared__ float tile[32][33];
    int tx = threadIdx.x & 31;
    int ty = threadIdx.x >> 5;            // 0..7
    for (int j = 0; j < 4; ++j)
        tile[ty + j * 8][tx] = src[(size_t)(k0 + ty + j * 8) * N + n0 + tx];
    __syncthreads();
    for (int j = 0; j < 4; ++j)
        dst[(size_t)(n0 + ty + j * 8) * K + k0 + tx] = f2bf(tile[tx][ty + j * 8]);
}

// ---------------------------------------------------------------------------
// V transpose: vb [B][T][NKV][HD] bf16 -> Vt [B][NKV][HD][T] bf16
// ---------------------------------------------------------------------------
__global__ void transpose_v(const u16* __restrict__ vb, u16* __restrict__ Vt) {
    int bx   = blockIdx.x;
    int dblk = bx & 1;
    int t0   = (bx >> 1) * 32;
    int kvh  = blockIdx.y, b = blockIdx.z;
    int dl   = threadIdx.x & 63;
    int tc   = threadIdx.x >> 6;     // 0..3
    int d    = dblk * 64 + dl;
    u16x8 v8;
    for (int j = 0; j < 8; ++j) {
        int t = t0 + tc * 8 + j;
        v8[j] = vb[((size_t)(b * T_ + t) * NKV_ + kvh) * HD_ + d];
    }
    *(u16x8*)(Vt + ((size_t)((b * NKV_ + kvh) * HD_ + d)) * T_ + t0 + tc * 8) = v8;
}

// ---------------------------------------------------------------------------
// RMSNorm over rows of [M][2048] f32 -> bf16
// ---------------------------------------------------------------------------
__global__ void rmsnorm_rows(const float* __restrict__ x, u16* __restrict__ out) {
    int row = blockIdx.x;
    const float4* xr = (const float4*)(x + (size_t)row * C_);
    float4 a = xr[threadIdx.x];
    float4 b = xr[threadIdx.x + 256];
    float ss = a.x * a.x + a.y * a.y + a.z * a.z + a.w * a.w
             + b.x * b.x + b.y * b.y + b.z * b.z + b.w * b.w;
    for (int m = 1; m < 64; m <<= 1) ss += __shfl_xor(ss, m, 64);
    __shared__ float part[4];
    if ((threadIdx.x & 63) == 0) part[threadIdx.x >> 6] = ss;
    __syncthreads();
    float tot = part[0] + part[1] + part[2] + part[3];
    float sc = rsqrtf(tot * (1.0f / C_) + EPS_);
    u16x4 o1, o2;
    o1[0] = f2bf(a.x * sc); o1[1] = f2bf(a.y * sc); o1[2] = f2bf(a.z * sc); o1[3] = f2bf(a.w * sc);
    o2[0] = f2bf(b.x * sc); o2[1] = f2bf(b.y * sc); o2[2] = f2bf(b.z * sc); o2[3] = f2bf(b.w * sc);
    u16x4* orow = (u16x4*)(out + (size_t)row * C_);
    orow[threadIdx.x]       = o1;
    orow[threadIdx.x + 256] = o2;
}

// ---------------------------------------------------------------------------
// Fused split-K reduce + residual + RMSNorm:
//   x2 = x + p0 + p1 (bf16 partials);  hout = rmsnorm(x2) bf16
// NOTE: p0 may alias hout (read-before-write, same indices).
// ---------------------------------------------------------------------------
__global__ void reduce_rms(const float* __restrict__ x, const u16* __restrict__ p0,
                           const u16* __restrict__ p1, float* __restrict__ x2,
                           u16* __restrict__ hout) {
    int row = blockIdx.x;
    const float4* xr = (const float4*)(x + (size_t)row * C_);
    const u16x4* a0 = (const u16x4*)(p0 + (size_t)row * C_);
    const u16x4* a1 = (const u16x4*)(p1 + (size_t)row * C_);
    float4 v[2];
    float ss = 0.f;
    for (int h = 0; h < 2; ++h) {
        int idx = threadIdx.x + h * 256;
        float4 xv = xr[idx];
        u16x4 b0 = a0[idx], b1 = a1[idx];
        v[h].x = xv.x + bf2f(b0[0]) + bf2f(b1[0]);
        v[h].y = xv.y + bf2f(b0[1]) + bf2f(b1[1]);
        v[h].z = xv.z + bf2f(b0[2]) + bf2f(b1[2]);
        v[h].w = xv.w + bf2f(b0[3]) + bf2f(b1[3]);
        ss += v[h].x * v[h].x + v[h].y * v[h].y + v[h].z * v[h].z + v[h].w * v[h].w;
    }
    for (int m = 1; m < 64; m <<= 1) ss += __shfl_xor(ss, m, 64);
    __shared__ float part[4];
    if ((threadIdx.x & 63) == 0) part[threadIdx.x >> 6] = ss;
    __syncthreads();
    float tot = part[0] + part[1] + part[2] + part[3];
    float sc = rsqrtf(tot * (1.0f / C_) + EPS_);
    float4* x2r = (float4*)(x2 + (size_t)row * C_);
    u16x4* hr   = (u16x4*)(hout + (size_t)row * C_);
    for (int h = 0; h < 2; ++h) {
        int idx = threadIdx.x + h * 256;
        x2r[idx] = v[h];
        u16x4 o;
        o[0] = f2bf(v[h].x * sc); o[1] = f2bf(v[h].y * sc);
        o[2] = f2bf(v[h].z * sc); o[3] = f2bf(v[h].w * sc);
        hr[idx] = o;
    }
}

// ---------------------------------------------------------------------------
// Final split-K reduce + residual: out = x2 + p0 + p1  (elementwise, f32)
// ---------------------------------------------------------------------------
__global__ void reduce_out(const float* __restrict__ x2, const u16* __restrict__ p0,
                           const u16* __restrict__ p1, float* __restrict__ out) {
    size_t i = (size_t)blockIdx.x * 256 + threadIdx.x;
    float4 xv = ((const float4*)x2)[i];
    u16x4 b0 = ((const u16x4*)p0)[i];
    u16x4 b1 = ((const u16x4*)p1)[i];
    float4 o;
    o.x = xv.x + bf2f(b0[0]) + bf2f(b1[0]);
    o.y = xv.y + bf2f(b0[1]) + bf2f(b1[1]);
    o.z = xv.z + bf2f(b0[2]) + bf2f(b1[2]);
    o.w = xv.w + bf2f(b0[3]) + bf2f(b1[3]);
    ((float4*)out)[i] = o;
}

// ---------------------------------------------------------------------------
// RoPE + per-head RMSNorm for BOTH q and k in one launch. One wave per row.
// ---------------------------------------------------------------------------
__global__ void rope_rms2(const float* __restrict__ Xq, const float* __restrict__ Xk,
                          const float* __restrict__ cosb, const float* __restrict__ sinb,
                          u16* __restrict__ Oq, u16* __restrict__ Ok) {
    int gw   = (int)((blockIdx.x * blockDim.x + threadIdx.x) >> 6);
    int lane = threadIdx.x & 63;
    const float* X; u16* O; int t;
    if (gw < B_ * T_ * NH_) {
        X = Xq + (size_t)gw * HD_;  O = Oq + (size_t)gw * HD_;  t = (gw / NH_) % T_;
    } else {
        int w2 = gw - B_ * T_ * NH_;
        X = Xk + (size_t)w2 * HD_;  O = Ok + (size_t)w2 * HD_;  t = (w2 / NKV_) % T_;
    }
    float x1 = X[lane];
    float x2 = X[64 + lane];
    float c  = cosb[t * 64 + lane];
    float sn = sinb[t * 64 + lane];
    float r1 = x1 * c + x2 * sn;
    float r2 = x2 * c - x1 * sn;
    float ss = r1 * r1 + r2 * r2;
    for (int m = 1; m < 64; m <<= 1) ss += __shfl_xor(ss, m, 64);
    float sc = rsqrtf(ss * (1.0f / HD_) + EPS_);
    O[lane]      = f2bf(r1 * sc);
    O[64 + lane] = f2bf(r2 * sc);
}

// ---------------------------------------------------------------------------
// Pipelined GEMM: C[M][N] = A[M][Ks](bf16) * Bt[N][Ks](bf16)^T, 128x128 tile,
// double-buffered, one barrier/step. K = per-block K extent (loop bound),
// Ks = row stride; blockIdx.z selects the K-chunk (split-K).
// EPI: 2=relu^2->bf16, 4=qkv routing, 5=split-K bf16 partial (z=0 -> out,
//      z=1 -> out2)
// ---------------------------------------------------------------------------
template <int EPI>
__launch_bounds__(256, 2)
__global__ void gemm_bt(const u16* __restrict__ A, const u16* __restrict__ Bt,
                        void* __restrict__ out, const float* __restrict__ res,
                        void* __restrict__ out2, void* __restrict__ out3,
                        int M, int N, int K, int Ks) {
    __shared__ __attribute__((aligned(16))) u16 As[2][128 * 32];
    __shared__ __attribute__((aligned(16))) u16 Bs[2][128 * 32];
    int tid  = threadIdx.x;
    int lane = tid & 63;
    int wave = tid >> 6;
    int quad = lane >> 4;
    int l16  = lane & 15;
    int bn = blockIdx.x, bm = blockIdx.y;
    int wm = wave >> 1, wn = wave & 1;

    int srow = lane >> 2;                                   // 0..15
    int scol = (((lane & 3) ^ (srow & 3))) * 8;             // swizzled source chunk
    size_t koff = (size_t)blockIdx.z * K;
    const u16* Ag = A  + (size_t)(bm * 128 + wave * 32 + srow) * Ks + scol + koff;
    const u16* Bg = Bt + (size_t)(bn * 128 + wave * 32 + srow) * Ks + scol + koff;

    auto stage = [&](int kk, int buf) {
        u16* Ab = &As[buf][(wave * 32) * 32];
        u16* Bb = &Bs[buf][(wave * 32) * 32];
        load_lds16(Ag + kk,                   Ab);
        load_lds16(Ag + kk + (size_t)16 * Ks, Ab + 16 * 32);
        load_lds16(Bg + kk,                   Bb);
        load_lds16(Bg + kk + (size_t)16 * Ks, Bb + 16 * 32);
    };

    f32x4 zero = {0.f, 0.f, 0.f, 0.f};
    f32x4 acc[4][4];
    for (int i = 0; i < 4; ++i)
        for (int j = 0; j < 4; ++j) acc[i][j] = zero;

    int rsw = (l16 & 3);
    stage(0, 0);
    int cur = 0;
    for (int k0 = 0; k0 < K; k0 += 32, cur ^= 1) {
        __syncthreads();
        if (k0 + 32 < K) stage(k0 + 32, cur ^ 1);
        bf16x8 af[4], bfr[4];
        int cs = (quad ^ rsw) * 8;
        for (int t = 0; t < 4; ++t) {
            af[t]  = *(const bf16x8*)&As[cur][(wm * 64 + t * 16 + l16) * 32 + cs];
            bfr[t] = *(const bf16x8*)&Bs[cur][(wn * 64 + t * 16 + l16) * 32 + cs];
        }
        for (int i = 0; i < 4; ++i)
            for (int j = 0; j < 4; ++j)
                acc[i][j] = __builtin_amdgcn_mfma_f32_16x16x32_bf16(af[i], bfr[j], acc[i][j], 0, 0, 0);
    }

    for (int i = 0; i < 4; ++i)
        for (int j = 0; j < 4; ++j)
            for (int r = 0; r < 4; ++r) {
                int rg = bm * 128 + wm * 64 + i * 16 + quad * 4 + r;
                int cg = bn * 128 + wn * 64 + j * 16 + l16;
                float v = acc[i][j][r];
                if (EPI == 2) {
                    float t = fmaxf(v, 0.f);
                    ((u16*)out)[(size_t)rg * N + cg] = f2bf(t * t);
                } else if (EPI == 4) {          // fused qkv routing
                    if (cg < 2048)      ((float*)out)[(size_t)rg * 2048 + cg] = v;
                    else if (cg < 2560) ((float*)out2)[(size_t)rg * 512 + (cg - 2048)] = v;
                    else                ((u16*)out3)[(size_t)rg * 512 + (cg - 2560)] = f2bf(v);
                } else {                        // EPI 5: split-K bf16 partial
                    u16* p = (blockIdx.z == 0) ? (u16*)out : (u16*)out2;
                    p[(size_t)rg * N + cg] = f2bf(v);
                }
            }
}

// ---------------------------------------------------------------------------
// Flash attention, causal GQA (unchanged from R3).
// ---------------------------------------------------------------------------
__launch_bounds__(256, 2)
__global__ void flash_attn2(const u16* __restrict__ Q, const u16* __restrict__ Kb,
                            const u16* __restrict__ Vt, u16* __restrict__ Y) {
    __shared__ __attribute__((aligned(16))) u16 Qs[128 * 128];
    __shared__ __attribute__((aligned(16))) u16 Ks[64 * 128];
    __shared__ __attribute__((aligned(16))) u16 Vs[128 * 64];

    int bid = blockIdx.x;
    int half = bid >> 8, idx = bid & 255;
    int qr = idx & 15;
    int qt = half ? (15 - qr) : qr;
    int bh = (idx >> 4) | (half << 4);
    int b = bh >> 4, h = bh & 15;
    int kvh = h >> 2;
    int q0 = qt * 128;

    int tid = threadIdx.x, lane = tid & 63, wave = tid >> 6;
    int quad = lane >> 4, l16 = lane & 15;

    {   // stage this wave's 32 Q rows (swizzled source chunk)
        int r = lane >> 4;
        for (int c = 0; c < 8; ++c) {
            int row = wave * 32 + c * 4 + r;
            int cc = ((lane & 15) ^ (row & 15)) * 8;
            const u16* g = Q + ((size_t)((b * T_ + q0 + row) * NH_ + h)) * HD_ + cc;
            load_lds16(g, &Qs[(wave * 32 + c * 4) * 128]);
        }
    }
    __syncthreads();

    bf16x8 qf[2][4];
    for (int qtile = 0; qtile < 2; ++qtile)
        for (int kd = 0; kd < 4; ++kd)
            qf[qtile][kd] = *(const bf16x8*)&Qs[(wave * 32 + qtile * 16 + l16) * 128
                                               + (((kd * 4 + quad) ^ l16) * 8)];
    u16* Ps = &Qs[wave * 32 * 128];   // dead Qs slice -> P buffer [32][72]

    f32x4 zero = {0.f, 0.f, 0.f, 0.f};
    f32x4 o[2][8];
    for (int qtile = 0; qtile < 2; ++qtile)
        for (int dt = 0; dt < 8; ++dt) o[qtile][dt] = zero;
    float m_i[2] = {-__builtin_inff(), -__builtin_inff()};
    float l_i[2] = {0.f, 0.f};
    const float s2s = 0.08838834764831845f * 1.4426950408889634f;  // scale*log2e

    int nkt = 2 * qt + 2;
    for (int kt = 0; kt < nkt; ++kt) {
        __syncthreads();
        {   // stage K: 16 rows per wave, swizzled
            int r = lane >> 4;
            for (int c = 0; c < 4; ++c) {
                int row = wave * 16 + c * 4 + r;
                int cc = ((lane & 15) ^ (row & 15)) * 8;
                const u16* g = Kb + ((size_t)((b * T_ + kt * 64 + row) * NKV_ + kvh)) * HD_ + cc;
                load_lds16(g, &Ks[(wave * 16 + c * 4) * 128]);
            }
        }
        {   // stage V^T: 32 d-rows per wave, swizzled ((d&7) key)
            int dr = lane >> 3;
            int kc = (((lane & 7) ^ dr)) * 8;
            for (int c = 0; c < 4; ++c) {
                int drow = wave * 32 + c * 8 + dr;
                const u16* g = Vt + ((size_t)((b * NKV_ + kvh) * HD_ + drow)) * T_ + kt * 64 + kc;
                load_lds16(g, &Vs[(wave * 32 + c * 8) * 64]);
            }
        }
        __syncthreads();

        f32x4 st[2][4];
        for (int qtile = 0; qtile < 2; ++qtile)
            for (int tn = 0; tn < 4; ++tn) st[qtile][tn] = zero;
        for (int tn = 0; tn < 4; ++tn)
            for (int kd = 0; kd < 4; ++kd) {
                bf16x8 kf = *(const bf16x8*)&Ks[(tn * 16 + l16) * 128
                                                + (((kd * 4 + quad) ^ l16) * 8)];
                st[0][tn] = __builtin_amdgcn_mfma_f32_16x16x32_bf16(kf, qf[0][kd], st[0][tn], 0, 0, 0);
                st[1][tn] = __builtin_amdgcn_mfma_f32_16x16x32_bf16(kf, qf[1][kd], st[1][tn], 0, 0, 0);
            }

        for (int qtile = 0; qtile < 2; ++qtile) {
            int qmin = q0 + wave * 32 + qtile * 16;
            int qg   = qmin + l16;
            bool need_mask = (kt * 64 + 63 > qmin);
            float mx = -__builtin_inff();
            for (int tn = 0; tn < 4; ++tn)
                for (int r = 0; r < 4; ++r) {
                    float v = st[qtile][tn][r] * s2s;
                    if (need_mask) {
                        int key = kt * 64 + tn * 16 + quad * 4 + r;
                        if (key > qg) v = -__builtin_inff();
                    }
                    st[qtile][tn][r] = v;
                    mx = fmaxf(mx, v);
                }
            mx = fmaxf(mx, __shfl_xor(mx, 16, 64));
            mx = fmaxf(mx, __shfl_xor(mx, 32, 64));
            float mnew = fmaxf(m_i[qtile], mx);
            float al   = exp2f(m_i[qtile] - mnew);
            m_i[qtile] = mnew;
            float sum = 0.f;
            for (int tn = 0; tn < 4; ++tn) {
                u16x4 pk;
                for (int r = 0; r < 4; ++r) {
                    float e = exp2f(st[qtile][tn][r] - mnew);
                    sum += e;
                    pk[r] = f2bf(e);
                }
                *(u16x4*)&Ps[(qtile * 16 + l16) * 72 + tn * 16 + quad * 4] = pk;
            }
            sum += __shfl_xor(sum, 16, 64);
            sum += __shfl_xor(sum, 32, 64);
            l_i[qtile] = l_i[qtile] * al + sum;
            float aB[4];
            for (int r = 0; r < 4; ++r) aB[r] = __shfl(al, quad * 4 + r, 64);
            for (int dt = 0; dt < 8; ++dt)
                for (int r = 0; r < 4; ++r) o[qtile][dt][r] *= aB[r];
        }

        bf16x8 pf[2][2];
        for (int qtile = 0; qtile < 2; ++qtile)
            for (int ks = 0; ks < 2; ++ks)
                pf[qtile][ks] = *(const bf16x8*)&Ps[(qtile * 16 + l16) * 72 + ks * 32 + quad * 8];
        for (int ks = 0; ks < 2; ++ks)
            for (int dt = 0; dt < 8; ++dt) {
                bf16x8 vf = *(const bf16x8*)&Vs[(dt * 16 + l16) * 64
                                                + (((ks * 4 + quad) ^ (l16 & 7)) * 8)];
                o[0][dt] = __builtin_amdgcn_mfma_f32_16x16x32_bf16(pf[0][ks], vf, o[0][dt], 0, 0, 0);
                o[1][dt] = __builtin_amdgcn_mfma_f32_16x16x32_bf16(pf[1][ks], vf, o[1][dt], 0, 0, 0);
            }
    }

    for (int qtile = 0; qtile < 2; ++qtile) {
        float inv = 1.0f / l_i[qtile];
        float iB[4];
        for (int r = 0; r < 4; ++r) iB[r] = __shfl(inv, quad * 4 + r, 64);
        for (int r = 0; r < 4; ++r) {
            int qg = q0 + wave * 32 + qtile * 16 + quad * 4 + r;
            u16* yr = Y + ((size_t)((b * T_ + qg) * NH_ + h)) * HD_;
            for (int dt = 0; dt < 8; ++dt)
                yr[dt * 16 + l16] = f2bf(o[qtile][dt][r] * iB[r]);
        }
    }
}

// ---------------------------------------------------------------------------
extern "C" void kernel_launch(void* const* d_in, const int* in_sizes, int n_in,
                              void* d_out, int out_size, void* d_ws, size_t ws_size,
                              hipStream_t stream) {
    const float* x     = (const float*)d_in[0];
    const float* cosb  = (const float*)d_in[1];
    const float* sinb  = (const float*)d_in[2];
    const float* wq    = (const float*)d_in[3];
    const float* wk    = (const float*)d_in[4];
    const float* wv    = (const float*)d_in[5];
    const float* wo    = (const float*)d_in[6];
    const float* wfc   = (const float*)d_in[7];
    const float* wproj = (const float*)d_in[8];

    char* ws = (char*)d_ws;
    size_t off = 0;
    auto alloc = [&](size_t bytes) { char* p = ws + off; off += (bytes + 255) & ~(size_t)255; return p; };

    u16*   wqkvT  = (u16*)alloc((size_t)3072 * C_ * 2);        // rows: q | k | v
    u16*   woT    = (u16*)alloc((size_t)C_ * C_ * 2);
    u16*   wfcT   = (u16*)alloc((size_t)DFF_ * C_ * 2);        // [8192][2048]
    u16*   wprojT = (u16*)alloc((size_t)C_ * DFF_ * 2);        // [2048][8192]
    u16*   hbuf   = (u16*)alloc((size_t)B_ * T_ * C_ * 2);     // h / p0 buffers
    float* x2     = (float*)alloc((size_t)B_ * T_ * C_ * 4);   // post-attn residual
    u16*   ybuf   = (u16*)alloc((size_t)B_ * T_ * C_ * 2);     // attn out / proj p1
    u16*   Vtb    = (u16*)alloc((size_t)B_ * NKV_ * HD_ * T_ * 2);  // V transposed
    // 64MB scratch: qkv temporaries -> wo partial p1 -> ffbuf
    char*  scratch = alloc((size_t)B_ * T_ * DFF_ * 2);
    float* q_tmp  = (float*)scratch;                                     // 32MB
    float* k_tmp  = (float*)(scratch + (size_t)B_ * T_ * C_ * 4);        // 8MB
    u16*   qb     = (u16*)(scratch + (size_t)B_ * T_ * C_ * 4 + (size_t)B_ * T_ * 512 * 4);
    u16*   kb     = (u16*)((char*)qb + (size_t)B_ * T_ * C_ * 2);
    u16*   vb     = (u16*)((char*)kb + (size_t)B_ * T_ * 512 * 2);
    u16*   wop1   = (u16*)scratch;       // wo split-K partial 1 (q_tmp dead by then)
    u16*   ffbuf  = (u16*)scratch;       // [4096][8192] bf16 (after reduce_rms)

    const int M = B_ * T_;   // 4096
    dim3 tb(256);

    // 1. weights -> bf16 [N][K] in ONE launch
    TD6 td;
    td.t[0] = { wq,    wqkvT,                       C_,   C_,   0 };
    td.t[1] = { wk,    wqkvT + (size_t)2048 * C_,   C_,   512,  4096 };
    td.t[2] = { wv,    wqkvT + (size_t)2560 * C_,   C_,   512,  5120 };
    td.t[3] = { wo,    woT,                         C_,   C_,   6144 };
    td.t[4] = { wfc,   wfcT,                        C_,   DFF_, 10240 };
    td.t[5] = { wproj, wprojT,                      DFF_, C_,   26624 };
    transpose_cast_all<<<dim3(43008), tb, 0, stream>>>(td);

    // 2. h = rmsnorm(x)
    rmsnorm_rows<<<M, tb, 0, stream>>>(x, hbuf);

    // 3. fused q/k/v projection (N=3072, 768 blocks = 3/CU)
    gemm_bt<4><<<dim3(3072 / 128, M / 128), tb, 0, stream>>>(hbuf, wqkvT, q_tmp, nullptr, k_tmp, vb, M, 3072, C_, C_);

    // 4. RoPE + qk-rmsnorm; V global transpose
    rope_rms2<<<dim3((B_ * T_ * (NH_ + NKV_)) / 4), tb, 0, stream>>>(q_tmp, k_tmp, cosb, sinb, qb, kb);
    transpose_v<<<dim3(128, NKV_, B_), tb, 0, stream>>>(vb, Vtb);

    // 5. causal GQA flash attention (512 blocks, 2/CU)
    flash_attn2<<<dim3(512), tb, 0, stream>>>(qb, kb, Vtb, ybuf);

    // 6. wo split-K=2: partials -> hbuf (z=0), wop1 (z=1); grid 1024 = 4/CU
    gemm_bt<5><<<dim3(C_ / 128, M / 128, 2), tb, 0, stream>>>(ybuf, woT, hbuf, nullptr, wop1, nullptr, M, C_, C_ / 2, C_);

    // 7. x2 = x + p0 + p1;  hbuf = rmsnorm(x2)   (p0 aliases hbuf — safe)
    reduce_rms<<<M, tb, 0, stream>>>(x, hbuf, wop1, x2, hbuf);

    // 8. ff = relu(h2 @ w_fc)^2   (ffbuf overwrites scratch after step 7)
    gemm_bt<2><<<dim3(DFF_ / 128, M / 128), tb, 0, stream>>>(hbuf, wfcT, ffbuf, nullptr, nullptr, nullptr, M, DFF_, C_, C_);

    // 9. proj split-K=2: partials -> hbuf (z=0), ybuf (z=1); grid 1024 = 4/CU
    gemm_bt<5><<<dim3(C_ / 128, M / 128, 2), tb, 0, stream>>>(ffbuf, wprojT, hbuf, nullptr, ybuf, nullptr, M, C_, DFF_ / 2, DFF_);

    // 10. out = x2 + p0 + p1
    reduce_out<<<dim3((M * C_) / 1024), tb, 0, stream>>>(x2, hbuf, ybuf, (float*)d_out);
}